// Round 6
// baseline (2834.222 us; speedup 1.0000x reference)
//
#include <hip/hip_runtime.h>
#include <hip/hip_cooperative_groups.h>
#include <hip/hip_bf16.h>
#include <math.h>
#include <stdint.h>

namespace cg = cooperative_groups;

typedef unsigned int u32;
typedef unsigned long long u64;

#define NM   65536
#define HD   1024
#define KS   128
#define SQ   258
#define NL   4
#define NBIN 65536
#define CCAP 2048
#define NBLK 240
#define NT   256

using bf16x8 = __attribute__((ext_vector_type(8))) short;
using f32x4v = __attribute__((ext_vector_type(4))) float;

struct Ctrl { u32 b1, above1, T, candcnt; };

static constexpr size_t A256(size_t x){ return (x + 255) & ~(size_t)255; }

// ---- zeroed-at-launch region (ONE memset) ----
constexpr size_t OFF_H3   = 0;                                  // 3*NBIN u32
constexpr size_t OFF_C3   = OFF_H3 + (size_t)3*NBIN*4;          // 3*NBIN u32
constexpr size_t OFF_HS   = OFF_C3 + (size_t)3*NBIN*4;          // NBIN u32
constexpr size_t OFF_VP   = OFF_HS + (size_t)NBIN*4;            // 129 f32 (+pad)
constexpr size_t ZERO_BYTES = OFF_VP + 1024;
// ---- rest ----
constexpr size_t OFF_P3   = A256(ZERO_BYTES);                       // 3*(NBIN+1) u32
constexpr size_t OFF_K3   = A256(OFF_P3 + (size_t)3*(NBIN+1)*4);    // 3*NM u32
constexpr size_t OFF_L3   = A256(OFF_K3 + (size_t)3*NM*4);          // 3*NM u32
constexpr size_t OFF_KSC  = A256(OFF_L3 + (size_t)3*NM*4);          // NM u32
constexpr size_t OFF_CAND = A256(OFF_KSC + (size_t)NM*4);           // CCAP u64
constexpr size_t OFF_CTRL = A256(OFF_CAND + (size_t)CCAP*8);
constexpr size_t OFF_IDX  = A256(OFF_CTRL + 256);
constexpr size_t OFF_HM   = A256(OFF_IDX  + (size_t)KS*4);
constexpr size_t OFF_HT   = A256(OFF_HM   + (size_t)KS*HD*4);
constexpr size_t OFF_REW  = A256(OFF_HT   + (size_t)KS*HD*4);
constexpr size_t OFF_VECS = A256(OFF_REW  + (size_t)KS*4);
constexpr size_t OFF_LNB  = A256(OFF_VECS + (size_t)SQ*HD*4);
constexpr size_t OFF_QKV  = A256(OFF_LNB  + (size_t)SQ*HD*4);
constexpr size_t OFF_ATT  = A256(OFF_QKV  + (size_t)SQ*3*HD*4);
constexpr size_t OFF_FFH  = A256(OFF_ATT  + (size_t)SQ*HD*4);
constexpr size_t OFF_PART = A256(OFF_FFH  + (size_t)SQ*4*HD*4);   // 2 x 4*SQ*HD f32

// output layout (floats)
constexpr int OUT_NEXT = 257*HD;
constexpr int OUT_VP   = OUT_NEXT + KS*HD;
constexpr int OUT_LOSS = OUT_VP + 1;
constexpr int OUT_REWO = OUT_LOSS + KS;

struct P {
  const float *x,*mv,*mnv,*surp,*mrew,*noise;
  const int *aim,*ait;
  const float *start,*pos;
  const float *inW,*inB,*oW,*oB,*l1w,*l1b,*l2w,*l2b,*f1w,*f1b,*f2w,*f2b;
  const float *amw1,*amb1,*amw2,*amb2,*atw1,*atb1,*atw2,*atb2;
  const float *vw1,*vb1,*vw2,*vb2;
  float *out;
  u32 *hist3,*cnt3,*histS; float *vp;
  u32 *pref3,*keys3,*lo3,*keysS; u64 *cand; Ctrl *ctrl; int *idx;
  float *hm,*ht,*rew,*vecs,*lnb,*qkvb,*attn,*ffh,*part,*part2;
};

__device__ __forceinline__ float gelu_f(float v){
  return 0.5f*v*(1.0f + erff(v*0.70710678118654752440f));
}

__device__ __forceinline__ short f2bf(float f){
  __hip_bfloat16 h = __float2bfloat16(f);
  short s;
  __builtin_memcpy(&s, &h, sizeof(short));
  return s;
}

__device__ __forceinline__ u32 fkey(float v){
  u32 b = __float_as_uint(v);
  return (b >> 31) ? ~b : (b | 0x80000000u);
}

// LN of a row distributed as thread t holds elements [4t,4t+4). red = 256-float smem.
__device__ float4 ln_apply(float4 v, const float* __restrict__ w, const float* __restrict__ b,
                           int j, float* red, int t){
  red[t] = v.x+v.y+v.z+v.w; __syncthreads();
  for(int o=128;o>0;o>>=1){ if(t<o) red[t]+=red[t+o]; __syncthreads(); }
  float m = red[0]*(1.0f/HD); __syncthreads();
  float dx=v.x-m, dy=v.y-m, dz=v.z-m, dw=v.w-m;
  red[t] = dx*dx+dy*dy+dz*dz+dw*dw; __syncthreads();
  for(int o=128;o>0;o>>=1){ if(t<o) red[t]+=red[t+o]; __syncthreads(); }
  float den = sqrtf(red[0]*(1.0f/HD) + 1e-5f); __syncthreads();
  float4 w4 = *(const float4*)&w[j];
  float4 b4 = *(const float4*)&b[j];
  float4 o4;
  o4.x = dx/den*w4.x + b4.x; o4.y = dy/den*w4.y + b4.y;
  o4.z = dz/den*w4.z + b4.z; o4.w = dw/den*w4.w + b4.w;
  return o4;
}

// 64x64-tile bf16 MFMA GEMM, double-buffered LDS, one tile per call.
// A: [M][lda] fp32, B: [N][K] fp32. ACT: 0 none, 1 gelu, 2 gelu+dot(w2)->atomic vp.
__device__ void gemm_tile(char* smem, const float* __restrict__ A, const float* __restrict__ B,
                          const float* __restrict__ bias, float* __restrict__ Pout,
                          const float* __restrict__ w2, float* __restrict__ vp,
                          int M, int N, int K, int S, int nbm, int lda,
                          int tile, int ACT, bool DIRECT){
  short* As = (short*)smem;
  short* Bs = (short*)(smem + 8192);
  float* rsum = (float*)(smem + 16384);
  int bm = (tile % nbm) * 64;
  int tmp = tile / nbm;
  int z  = DIRECT ? 0 : (tmp % S);
  int bn = DIRECT ? tmp * 64 : (tmp / S) * 64;
  int Ks = K / S, kbeg = z*Ks;
  int nk = Ks >> 5;

  int t = threadIdx.x;
  int srow = t >> 2, sg = t & 3;
  int sgp = sg ^ ((srow >> 1) & 3);
  bool arow_ok = (bm + srow) < M;
  const float* ap = A + (size_t)(bm + srow)*lda + kbeg + sg*8;
  const float* bp = B + (size_t)(bn + srow)*K + kbeg + sg*8;
  int stoff = srow*32 + sgp*8;

  int lane = t & 63, w = t >> 6;
  int wm = (w >> 1)*32, wn = (w & 1)*32;
  int lr = lane & 15, lg = lane >> 4;
  int ra0 = wm + lr, ra1 = ra0 + 16;
  int rb0 = wn + lr, rb1 = rb0 + 16;
  int aoff0 = ra0*32 + (lg ^ ((ra0>>1)&3))*8;
  int aoff1 = ra1*32 + (lg ^ ((ra1>>1)&3))*8;
  int boff0 = rb0*32 + (lg ^ ((rb0>>1)&3))*8;
  int boff1 = rb1*32 + (lg ^ ((rb1>>1)&3))*8;

  f32x4v acc00 = {0,0,0,0}, acc01 = {0,0,0,0}, acc10 = {0,0,0,0}, acc11 = {0,0,0,0};

  {
    float4 va0 = {0,0,0,0}, va1 = {0,0,0,0};
    if(arow_ok){ va0 = *(const float4*)ap; va1 = *(const float4*)(ap+4); }
    float4 vb0 = *(const float4*)bp;
    float4 vb1 = *(const float4*)(bp+4);
    ap += 32; bp += 32;
    bf16x8 sa, sb;
    sa[0]=f2bf(va0.x); sa[1]=f2bf(va0.y); sa[2]=f2bf(va0.z); sa[3]=f2bf(va0.w);
    sa[4]=f2bf(va1.x); sa[5]=f2bf(va1.y); sa[6]=f2bf(va1.z); sa[7]=f2bf(va1.w);
    sb[0]=f2bf(vb0.x); sb[1]=f2bf(vb0.y); sb[2]=f2bf(vb0.z); sb[3]=f2bf(vb0.w);
    sb[4]=f2bf(vb1.x); sb[5]=f2bf(vb1.y); sb[6]=f2bf(vb1.z); sb[7]=f2bf(vb1.w);
    *(bf16x8*)&As[stoff] = sa;
    *(bf16x8*)&Bs[stoff] = sb;
  }
  __syncthreads();

  for(int kk = 0; kk < nk; ++kk){
    int cur = (kk & 1) << 11;
    bool more = (kk + 1) < nk;
    float4 va0, va1, vb0, vb1;
    if(more){
      va0 = make_float4(0,0,0,0); va1 = make_float4(0,0,0,0);
      if(arow_ok){ va0 = *(const float4*)ap; va1 = *(const float4*)(ap+4); }
      vb0 = *(const float4*)bp;
      vb1 = *(const float4*)(bp+4);
      ap += 32; bp += 32;
    }
    bf16x8 a0 = *(const bf16x8*)&As[cur + aoff0];
    bf16x8 a1 = *(const bf16x8*)&As[cur + aoff1];
    bf16x8 b0 = *(const bf16x8*)&Bs[cur + boff0];
    bf16x8 b1 = *(const bf16x8*)&Bs[cur + boff1];
    acc00 = __builtin_amdgcn_mfma_f32_16x16x32_bf16(a0, b0, acc00, 0, 0, 0);
    acc01 = __builtin_amdgcn_mfma_f32_16x16x32_bf16(a0, b1, acc01, 0, 0, 0);
    acc10 = __builtin_amdgcn_mfma_f32_16x16x32_bf16(a1, b0, acc10, 0, 0, 0);
    acc11 = __builtin_amdgcn_mfma_f32_16x16x32_bf16(a1, b1, acc11, 0, 0, 0);
    if(more){
      int nxt = cur ^ 2048;
      bf16x8 sa, sb;
      sa[0]=f2bf(va0.x); sa[1]=f2bf(va0.y); sa[2]=f2bf(va0.z); sa[3]=f2bf(va0.w);
      sa[4]=f2bf(va1.x); sa[5]=f2bf(va1.y); sa[6]=f2bf(va1.z); sa[7]=f2bf(va1.w);
      sb[0]=f2bf(vb0.x); sb[1]=f2bf(vb0.y); sb[2]=f2bf(vb0.z); sb[3]=f2bf(vb0.w);
      sb[4]=f2bf(vb1.x); sb[5]=f2bf(vb1.y); sb[6]=f2bf(vb1.z); sb[7]=f2bf(vb1.w);
      *(bf16x8*)&As[nxt + stoff] = sa;
      *(bf16x8*)&Bs[nxt + stoff] = sb;
    }
    __syncthreads();
  }

  if(ACT == 2){
    if(t < 64) rsum[t] = 0.f;
    __syncthreads();
    #pragma unroll
    for(int r=0;r<4;++r){
      int rl0 = wm + lg*4 + r, rl1 = rl0 + 16;
      int c0 = bn + wn + lr, c1 = c0 + 16;
      float v00 = gelu_f(acc00[r] + bias[c0]) * w2[c0];
      float v01 = gelu_f(acc01[r] + bias[c1]) * w2[c1];
      atomicAdd(&rsum[rl0], v00 + v01);
      float v10 = gelu_f(acc10[r] + bias[c0]) * w2[c0];
      float v11 = gelu_f(acc11[r] + bias[c1]) * w2[c1];
      atomicAdd(&rsum[rl1], v10 + v11);
    }
    __syncthreads();
    if(t < 64 && (bm + t) < M) atomicAdd(&vp[bm + t], rsum[t]);
    __syncthreads();
    return;
  }

  size_t zbase = (size_t)z * (size_t)M;
  #pragma unroll
  for(int r=0;r<4;++r){
    int row0 = bm + wm + lg*4 + r;
    int row1 = row0 + 16;
    int c0 = bn + wn + lr, c1 = c0 + 16;
    if(DIRECT){
      if(row0 < M){
        float v0 = acc00[r] + bias[c0], v1 = acc01[r] + bias[c1];
        if(ACT == 1){ v0 = gelu_f(v0); v1 = gelu_f(v1); }
        Pout[(size_t)row0*N + c0] = v0; Pout[(size_t)row0*N + c1] = v1;
      }
      if(row1 < M){
        float v0 = acc10[r] + bias[c0], v1 = acc11[r] + bias[c1];
        if(ACT == 1){ v0 = gelu_f(v0); v1 = gelu_f(v1); }
        Pout[(size_t)row1*N + c0] = v0; Pout[(size_t)row1*N + c1] = v1;
      }
    } else {
      if(row0 < M){
        Pout[(zbase+row0)*N + c0] = acc00[r];
        Pout[(zbase+row0)*N + c1] = acc01[r];
      }
      if(row1 < M){
        Pout[(zbase+row1)*N + c0] = acc10[r];
        Pout[(zbase+row1)*N + c1] = acc11[r];
      }
    }
  }
}

// attention for one q row: 4 teams of 64 lanes, each team loops heads h=team,team+4,...
__device__ void attn_q(char* smem, const float* __restrict__ qkv, float* __restrict__ outp, int q){
  int t = threadIdx.x, team = t >> 6, lane = t & 63;
  float* qs = (float*)smem + team*64;
  float* pl = (float*)(smem + 1024) + team*264;
  int nk = q + 1;
  for(int h = team; h < 16; h += 4){
    qs[lane] = qkv[(size_t)q*3072 + h*64 + lane];
    float pv[5]; float mx = -1e30f;
    #pragma unroll
    for(int rep=0;rep<5;++rep){
      int j = lane + rep*64;
      float s = -1e30f;
      if(j < nk){
        const float* kr = qkv + (size_t)j*3072 + 1024 + h*64;
        float d = 0.f;
        for(int c=0;c<64;++c) d += qs[c]*kr[c];
        s = d*0.125f;
      }
      pv[rep] = s; mx = fmaxf(mx, s);
    }
    for(int o=32;o>0;o>>=1) mx = fmaxf(mx, __shfl_xor(mx,o,64));
    float sum = 0.f;
    #pragma unroll
    for(int rep=0;rep<5;++rep){
      int j = lane + rep*64;
      if(j < nk){ float e = expf(pv[rep]-mx); pl[j] = e; sum += e; }
    }
    for(int o=32;o>0;o>>=1) sum += __shfl_xor(sum,o,64);
    float inv = 1.0f/sum;
    float acc = 0.f;
    for(int j=0;j<nk;++j) acc += pl[j]*qkv[(size_t)j*3072 + 2048 + h*64 + lane];
    outp[(size_t)q*HD + h*64 + lane] = acc*inv;
  }
}

// finrow: sum 4 partials + bias + residual -> vecs; then LN->lnb (mode0) or copy-out (mode1)
__device__ void finrow_task(char* smem, int t, int row, const float* __restrict__ Pp,
                            const float* __restrict__ bias, float* __restrict__ vecs,
                            const float* __restrict__ lw, const float* __restrict__ lb,
                            float* __restrict__ lnb, float* __restrict__ outp, int mode){
  int j = t*4;
  float4 v = *(const float4*)&Pp[(size_t)row*HD + j];
  #pragma unroll
  for(int z=1;z<4;++z){
    float4 q = *(const float4*)&Pp[((size_t)z*SQ + row)*HD + j];
    v.x += q.x; v.y += q.y; v.z += q.z; v.w += q.w;
  }
  float4 b4 = *(const float4*)&bias[j];
  float4 r4 = *(const float4*)&vecs[(size_t)row*HD + j];
  v.x += b4.x + r4.x; v.y += b4.y + r4.y; v.z += b4.z + r4.z; v.w += b4.w + r4.w;
  *(float4*)&vecs[(size_t)row*HD + j] = v;
  if(mode == 0){
    float4 o4 = ln_apply(v, lw, lb, j, (float*)(smem+8192), t);
    *(float4*)&lnb[(size_t)row*HD + j] = o4;
  } else {
    if(row >= 1) *(float4*)&outp[(size_t)(row-1)*HD + j] = v;
  }
}

__global__ __launch_bounds__(256) void mega(P p){
  cg::grid_group grid = cg::this_grid();
  __shared__ char smem[16896];
  const int bid = blockIdx.x, t = threadIdx.x;
  const int NBk = gridDim.x;

  // ---- P0: x-norm + sim + 3x keys + 3x hist ----
  {
    float* xs = (float*)smem;
    float* red = (float*)(smem + 8192);
    float s = 0.f;
    for(int i=t;i<HD;i+=NT){ float v=p.x[i]; s += v*v; }
    red[t]=s; __syncthreads();
    for(int o=128;o>0;o>>=1){ if(t<o) red[t]+=red[t+o]; __syncthreads(); }
    float nrm = fmaxf(sqrtf(red[0]), 1e-8f);
    for(int i=t;i<HD;i+=NT) xs[i] = p.x[i]/nrm;
    __syncthreads();
    int lane = t & 63, w = t >> 6;
    for(int task=bid; task<NM/4; task+=NBk){
      int row = task*4 + w;
      const float4* pr = (const float4*)(p.mv + (size_t)row*HD);
      const float4* q4 = (const float4*)xs;
      float d=0.f, ss=0.f;
      #pragma unroll
      for(int r=0;r<4;++r){
        float4 v = pr[lane + 64*r]; float4 u = q4[lane + 64*r];
        d  += v.x*u.x + v.y*u.y + v.z*u.z + v.w*u.w;
        ss += v.x*v.x + v.y*v.y + v.z*v.z + v.w*v.w;
      }
      for(int o=32;o>0;o>>=1){ d += __shfl_xor(d,o,64); ss += __shfl_xor(ss,o,64); }
      if(lane==0){
        float sim = d / fmaxf(sqrtf(ss),1e-8f);
        float vals[3] = { p.surp[row], sim, p.noise[row] };
        #pragma unroll
        for(int a=0;a<3;++a){
          u32 k = fkey(vals[a]);
          p.keys3[(size_t)a*NM + row] = k;
          atomicAdd(&p.hist3[(size_t)a*NBIN + (k >> 16)], 1u);
        }
      }
    }
  }
  grid.sync();

  // ---- P1: scan (3 tasks) ----
  {
    u32* part = (u32*)smem;
    for(int task=bid; task<3; task+=NBk){
      const u32* hist = p.hist3 + (size_t)task*NBIN;
      u32* prefix = p.pref3 + (size_t)task*(NBIN+1);
      u32 base = t*256, s = 0;
      for(int j=0;j<256;++j) s += hist[base+j];
      part[t] = s; __syncthreads();
      for(int off=1;off<256;off<<=1){
        u32 v = (t >= off) ? part[t-off] : 0u;
        __syncthreads(); part[t] += v; __syncthreads();
      }
      u32 run = part[t] - s;
      for(int j=0;j<256;++j){ prefix[base+j] = run; run += hist[base+j]; }
      if(t == 255) prefix[NBIN] = run;
    }
  }
  grid.sync();

  // ---- P2: scatter ----
  for(int i = bid*NT + t; i < NM; i += NBk*NT){
    #pragma unroll
    for(int a=0;a<3;++a){
      u32 k = p.keys3[(size_t)a*NM + i];
      u32 b = k >> 16;
      u32 pos = p.pref3[(size_t)a*(NBIN+1) + b] + atomicAdd(&p.cnt3[(size_t)a*NBIN + b], 1u);
      p.lo3[(size_t)a*NM + pos] = k & 0xFFFFu;
    }
  }
  grid.sync();

  // ---- P3: rank + score + score hist ----
  for(int i = bid*NT + t; i < NM; i += NBk*NT){
    float rr[3];
    #pragma unroll
    for(int a=0;a<3;++a){
      u32 k = p.keys3[(size_t)a*NM + i];
      u32 b = k >> 16, my = k & 0xFFFFu;
      const u32* pref = p.pref3 + (size_t)a*(NBIN+1);
      const u32* lo = p.lo3 + (size_t)a*NM;
      u32 s = pref[b], e = pref[b+1];
      u32 nl = 0, ne = 0;
      for(u32 j=s;j<e;++j){ u32 u = lo[j]; nl += (u < my); ne += (u == my); }
      u32 left = s + nl, right = left + ne;
      rr[a] = (float)(left + right - 1) * (1.0f/131072.0f);
    }
    float sc = __fadd_rn(__fadd_rn(__fmul_rn(rr[0],rr[0]), __fmul_rn(rr[1],rr[1])), __fmul_rn(rr[2],rr[2]));
    u32 k = __float_as_uint(sc);
    p.keysS[i] = k;
    atomicAdd(&p.histS[k >> 16], 1u);
  }
  grid.sync();

  // ---- P4: threshold select ----
  if(bid == 0){
    u32* part = (u32*)smem;
    u32 base = t*256, s = 0;
    for(int j=0;j<256;++j) s += p.histS[base+j];
    part[t] = s; __syncthreads();
    for(int off=1;off<256;off<<=1){
      u32 v = (t+off < 256) ? part[t+off] : 0u;
      __syncthreads(); part[t] += v; __syncthreads();
    }
    u32 above = part[t] - s;
    if(above < (u32)KS && above + s >= (u32)KS){
      u32 cum = above;
      for(int j=255;j>=0;--j){
        u32 c = p.histS[base+j];
        if(cum + c >= (u32)KS){ p.ctrl->T = (u32)(base+j) << 16; p.ctrl->candcnt = 0; break; }
        cum += c;
      }
    }
  }
  grid.sync();

  // ---- P5: collect candidates ----
  for(int i = bid*NT + t; i < NM; i += NBk*NT){
    u32 k = p.keysS[i];
    if(k >= p.ctrl->T){
      u32 pos = atomicAdd(&p.ctrl->candcnt, 1u);
      if(pos < (u32)CCAP) p.cand[pos] = ((u64)(~k) << 32) | (u32)i;
    }
  }
  grid.sync();

  // ---- P6: bitonic sort + select top-128 ----
  if(bid == 0){
    u64* sm = (u64*)smem;
    u32 n = p.ctrl->candcnt; if(n > (u32)CCAP) n = CCAP;
    for(int i=t;i<CCAP;i+=NT) sm[i] = (i < (int)n) ? p.cand[i] : 0xFFFFFFFFFFFFFFFFull;
    __syncthreads();
    for(int k=2;k<=CCAP;k<<=1){
      for(int j=k>>1;j>0;j>>=1){
        for(int i=t;i<CCAP;i+=NT){
          int ixj = i ^ j;
          if(ixj > i){
            bool up = ((i & k) == 0);
            u64 a = sm[i], b = sm[ixj];
            if((a > b) == up){ sm[i] = b; sm[ixj] = a; }
          }
        }
        __syncthreads();
      }
    }
    if(t < KS) p.idx[t] = (int)(sm[t] & 0xFFFFFFFFu);
  }
  grid.sync();

  // ---- S0: gather + act hidden + boundary rows ----
  for(int task=bid; task<KS+1; task+=NBk){
    if(task < KS){
      int row = p.idx[task];
      const float* a = p.mv  + (size_t)row*HD;
      const float* b = p.mnv + (size_t)row*HD;
      const float* pz = p.pos + (size_t)(2*task+1)*HD;
      float* vr = p.vecs + (size_t)(2*task+1)*HD;
      for(int c=t;c<HD;c+=NT){
        vr[c] = a[c] + pz[c];
        p.out[OUT_NEXT + task*HD + c] = b[c];
      }
      int am = p.aim[row], at = p.ait[row];
      for(int j=t;j<HD;j+=NT){
        p.hm[(size_t)task*HD+j] = gelu_f(p.amw1[(size_t)j*9 + am] + p.amb1[j]);
        p.ht[(size_t)task*HD+j] = gelu_f(p.atw1[(size_t)j*4 + at] + p.atb1[j]);
      }
      if(t == 0){ float r = p.mrew[row]; p.rew[task] = r; p.out[OUT_REWO + task] = r; }
    } else {
      for(int c=t;c<HD;c+=NT){
        p.vecs[c] = p.start[c] + p.pos[c];
        p.vecs[(size_t)(SQ-1)*HD + c] = p.x[c] + p.pos[(size_t)(SQ-1)*HD + c];
      }
    }
  }
  grid.sync();

  // ---- S1: action GEMM partials (2 gemms x 2x16 tiles x S4 = 256 tasks) ----
  for(int task=bid; task<256; task+=NBk){
    int which = task >> 7, tl = task & 127;
    gemm_tile(smem, which ? p.ht : p.hm, which ? p.atw2 : p.amw2, nullptr,
              which ? p.part2 : p.part, nullptr, nullptr,
              KS, HD, HD, 4, 2, HD, tl, 0, false);
  }
  grid.sync();

  // ---- S2: finav (even rows) + LN1 all rows ----
  for(int task=bid; task<SQ; task+=NBk){
    int j = t*4;
    float4 v;
    if(task >= 2 && task <= 256 && ((task & 1) == 0)){
      int k = (task-2) >> 1;
      float4 s = {0,0,0,0};
      #pragma unroll
      for(int z=0;z<4;++z){
        float4 a = *(const float4*)&p.part [((size_t)z*KS + k)*HD + j];
        float4 b = *(const float4*)&p.part2[((size_t)z*KS + k)*HD + j];
        s.x += a.x+b.x; s.y += a.y+b.y; s.z += a.z+b.z; s.w += a.w+b.w;
      }
      float4 bm4 = *(const float4*)&p.amb2[j];
      float4 bt4 = *(const float4*)&p.atb2[j];
      float4 p4 = *(const float4*)&p.pos[(size_t)task*HD + j];
      v.x = 0.5f*(s.x + bm4.x + bt4.x) + p4.x;
      v.y = 0.5f*(s.y + bm4.y + bt4.y) + p4.y;
      v.z = 0.5f*(s.z + bm4.z + bt4.z) + p4.z;
      v.w = 0.5f*(s.w + bm4.w + bt4.w) + p4.w;
      *(float4*)&p.vecs[(size_t)task*HD + j] = v;
    } else {
      v = *(const float4*)&p.vecs[(size_t)task*HD + j];
    }
    float4 o4 = ln_apply(v, p.l1w, p.l1b, j, (float*)(smem+8192), t);
    *(float4*)&p.lnb[(size_t)task*HD + j] = o4;
  }
  grid.sync();

  // ---- transformer layers ----
  for(int l=0;l<NL;++l){
    // qkv: 5x48 = 240 tiles, direct
    for(int task=bid; task<240; task+=NBk)
      gemm_tile(smem, p.lnb, p.inW + (size_t)l*3*HD*HD, p.inB + (size_t)l*3*HD,
                p.qkvb, nullptr, nullptr, SQ, 3*HD, HD, 1, 5, HD, task, 0, true);
    grid.sync();
    // attention: 258 q tasks
    for(int task=bid; task<SQ; task+=NBk)
      attn_q(smem, p.qkvb, p.attn, task);
    grid.sync();
    // o-proj partials: 5x16x4 = 320 tasks
    for(int task=bid; task<320; task+=NBk)
      gemm_tile(smem, p.attn, p.oW + (size_t)l*HD*HD, nullptr, p.part, nullptr, nullptr,
                SQ, HD, HD, 4, 5, HD, task, 0, false);
    grid.sync();
    // finrow + LN2
    for(int task=bid; task<SQ; task+=NBk)
      finrow_task(smem, t, task, p.part, p.oB + (size_t)l*HD, p.vecs,
                  p.l2w + (size_t)l*HD, p.l2b + (size_t)l*HD, p.lnb, nullptr, 0);
    grid.sync();
    // ffn1: 5x64 = 320 tiles, direct gelu
    for(int task=bid; task<320; task+=NBk)
      gemm_tile(smem, p.lnb, p.f1w + (size_t)l*4*HD*HD, p.f1b + (size_t)l*4*HD,
                p.ffh, nullptr, nullptr, SQ, 4*HD, HD, 1, 5, HD, task, 1, true);
    grid.sync();
    // ffn2 partials: 5x4x16 = 320 tasks, K=4096
    for(int task=bid; task<320; task+=NBk)
      gemm_tile(smem, p.ffh, p.f2w + (size_t)l*HD*4*HD, nullptr, p.part, nullptr, nullptr,
                SQ, HD, 4*HD, 4, 5, 4*HD, task, 0, false);
    grid.sync();
    // finrow + (LN1 next | copy out)
    for(int task=bid; task<SQ; task+=NBk){
      if(l < NL-1)
        finrow_task(smem, t, task, p.part, p.f2b + (size_t)l*HD, p.vecs,
                    p.l1w + (size_t)(l+1)*HD, p.l1b + (size_t)(l+1)*HD, p.lnb, nullptr, 0);
      else
        finrow_task(smem, t, task, p.part, p.f2b + (size_t)l*HD, p.vecs,
                    nullptr, nullptr, nullptr, p.out, 1);
    }
    grid.sync();
  }

  // ---- value head: 3x64 = 192 tiles, gelu+dot(w2) -> atomic vp ----
  for(int task=bid; task<192; task+=NBk)
    gemm_tile(smem, p.vecs + HD, p.vw1, p.vb1, nullptr, p.vw2, p.vp,
              KS+1, 4*HD, HD, 1, 3, 2*HD, task, 2, true);
  grid.sync();

  // ---- small outputs ----
  if(bid == 0){
    float bb = p.vb2[0];
    if(t == 0) p.out[OUT_VP] = p.vp[KS] + bb;
    if(t < KS){
      float d = (p.vp[t] + bb) - p.rew[t];
      p.out[OUT_LOSS + t] = d*d;
    }
  }
}

extern "C" void kernel_launch(void* const* d_in, const int* in_sizes, int n_in,
                              void* d_out, int out_size, void* d_ws, size_t ws_size,
                              hipStream_t stream){
  char* ws = (char*)d_ws;
  P prm;
  prm.x     = (const float*)d_in[0];
  prm.mv    = (const float*)d_in[1];
  prm.mnv   = (const float*)d_in[2];
  prm.surp  = (const float*)d_in[3];
  prm.mrew  = (const float*)d_in[4];
  prm.noise = (const float*)d_in[5];
  prm.aim   = (const int*)d_in[6];
  prm.ait   = (const int*)d_in[7];
  prm.start = (const float*)d_in[8];
  prm.pos   = (const float*)d_in[9];
  prm.inW = (const float*)d_in[10]; prm.inB = (const float*)d_in[11];
  prm.oW  = (const float*)d_in[12]; prm.oB  = (const float*)d_in[13];
  prm.l1w = (const float*)d_in[14]; prm.l1b = (const float*)d_in[15];
  prm.l2w = (const float*)d_in[16]; prm.l2b = (const float*)d_in[17];
  prm.f1w = (const float*)d_in[18]; prm.f1b = (const float*)d_in[19];
  prm.f2w = (const float*)d_in[20]; prm.f2b = (const float*)d_in[21];
  prm.amw1= (const float*)d_in[22]; prm.amb1= (const float*)d_in[23];
  prm.amw2= (const float*)d_in[24]; prm.amb2= (const float*)d_in[25];
  prm.atw1= (const float*)d_in[26]; prm.atb1= (const float*)d_in[27];
  prm.atw2= (const float*)d_in[28]; prm.atb2= (const float*)d_in[29];
  prm.vw1 = (const float*)d_in[30]; prm.vb1 = (const float*)d_in[31];
  prm.vw2 = (const float*)d_in[32]; prm.vb2 = (const float*)d_in[33];
  prm.out = (float*)d_out;
  prm.hist3 = (u32*)(ws+OFF_H3);
  prm.cnt3  = (u32*)(ws+OFF_C3);
  prm.histS = (u32*)(ws+OFF_HS);
  prm.vp    = (float*)(ws+OFF_VP);
  prm.pref3 = (u32*)(ws+OFF_P3);
  prm.keys3 = (u32*)(ws+OFF_K3);
  prm.lo3   = (u32*)(ws+OFF_L3);
  prm.keysS = (u32*)(ws+OFF_KSC);
  prm.cand  = (u64*)(ws+OFF_CAND);
  prm.ctrl  = (Ctrl*)(ws+OFF_CTRL);
  prm.idx   = (int*)(ws+OFF_IDX);
  prm.hm    = (float*)(ws+OFF_HM);
  prm.ht    = (float*)(ws+OFF_HT);
  prm.rew   = (float*)(ws+OFF_REW);
  prm.vecs  = (float*)(ws+OFF_VECS);
  prm.lnb   = (float*)(ws+OFF_LNB);
  prm.qkvb  = (float*)(ws+OFF_QKV);
  prm.attn  = (float*)(ws+OFF_ATT);
  prm.ffh   = (float*)(ws+OFF_FFH);
  prm.part  = (float*)(ws+OFF_PART);
  prm.part2 = prm.part + (size_t)4*SQ*HD;

  (void)hipMemsetAsync(ws, 0, ZERO_BYTES, stream);
  void* args[] = { &prm };
  (void)hipLaunchCooperativeKernel((const void*)mega, dim3(NBLK), dim3(NT), args, 0, stream);
}

// Round 7
// 972.733 us; speedup vs baseline: 2.9137x; 2.9137x over previous
//
#include <hip/hip_runtime.h>
#include <hip/hip_bf16.h>
#include <math.h>
#include <stdint.h>

typedef unsigned int u32;
typedef unsigned long long u64;

#define NM   65536
#define HD   1024
#define KS   128
#define SQ   258
#define NL   4
#define NBIN 65536
#define CCAP 2048

using bf16x8 = __attribute__((ext_vector_type(8))) short;
using f32x4v = __attribute__((ext_vector_type(4))) float;

struct Ctrl { u32 b1, above1, T, candcnt; };

static constexpr size_t A256(size_t x){ return (x + 255) & ~(size_t)255; }

// ---- zeroed-at-launch region (ONE memset) ----
constexpr size_t OFF_H3   = 0;                                  // 3*NBIN u32
constexpr size_t OFF_C3   = OFF_H3 + (size_t)3*NBIN*4;          // 3*NBIN u32
constexpr size_t OFF_HS   = OFF_C3 + (size_t)3*NBIN*4;          // NBIN u32
constexpr size_t ZERO_BYTES = OFF_HS + (size_t)NBIN*4;
// ---- rest ----
constexpr size_t OFF_BS   = A256(ZERO_BYTES);                       // 192 u32 block sums
constexpr size_t OFF_BB   = A256(OFF_BS + 192*4);                   // 192 u32 block bases
constexpr size_t OFF_VPB  = A256(OFF_BB + 192*4);                   // 129 f32
constexpr size_t OFF_XN   = A256(OFF_VPB + 1024);                   // HD f32
constexpr size_t OFF_P3   = A256(OFF_XN + (size_t)HD*4);            // 3*(NBIN+1) u32
constexpr size_t OFF_K3   = A256(OFF_P3 + (size_t)3*(NBIN+1)*4);    // 3*NM u32
constexpr size_t OFF_L3   = A256(OFF_K3 + (size_t)3*NM*4);          // 3*NM u32
constexpr size_t OFF_KSC  = A256(OFF_L3 + (size_t)3*NM*4);          // NM u32
constexpr size_t OFF_CAND = A256(OFF_KSC + (size_t)NM*4);           // CCAP u64
constexpr size_t OFF_CTRL = A256(OFF_CAND + (size_t)CCAP*8);
constexpr size_t OFF_IDX  = A256(OFF_CTRL + 256);
constexpr size_t OFF_HM   = A256(OFF_IDX  + (size_t)KS*4);
constexpr size_t OFF_HT   = A256(OFF_HM   + (size_t)KS*HD*4);
constexpr size_t OFF_REW  = A256(OFF_HT   + (size_t)KS*HD*4);
constexpr size_t OFF_VECS = A256(OFF_REW  + (size_t)KS*4);
constexpr size_t OFF_LNB  = A256(OFF_VECS + (size_t)SQ*HD*4);
constexpr size_t OFF_QKV  = A256(OFF_LNB  + (size_t)SQ*HD*4);
constexpr size_t OFF_ATT  = A256(OFF_QKV  + (size_t)SQ*3*HD*4);
constexpr size_t OFF_FFH  = A256(OFF_ATT  + (size_t)SQ*HD*4);
constexpr size_t OFF_PART = A256(OFF_FFH  + (size_t)SQ*4*HD*4);   // 2113536 f32 = 8.45 MB

// output layout (floats)
constexpr int OUT_NEXT = 257*HD;
constexpr int OUT_VP   = OUT_NEXT + KS*HD;
constexpr int OUT_LOSS = OUT_VP + 1;
constexpr int OUT_REWO = OUT_LOSS + KS;

__device__ __forceinline__ float gelu_f(float v){
  return 0.5f*v*(1.0f + erff(v*0.70710678118654752440f));
}

__device__ __forceinline__ short f2bf(float f){
  __hip_bfloat16 h = __float2bfloat16(f);
  short s;
  __builtin_memcpy(&s, &h, sizeof(short));
  return s;
}

__device__ __forceinline__ u32 fkey(float v){
  u32 b = __float_as_uint(v);
  return (b >> 31) ? ~b : (b | 0x80000000u);
}

// ----------------- xn (once) -----------------
__global__ void k_xn(const float* __restrict__ x, float* __restrict__ xn){
  __shared__ float red[256];
  int t = threadIdx.x;
  float s = 0.f;
  for(int i=t;i<HD;i+=256){ float v=x[i]; s += v*v; }
  red[t]=s; __syncthreads();
  for(int o=128;o>0;o>>=1){ if(t<o) red[t]+=red[t+o]; __syncthreads(); }
  float nrm = fmaxf(sqrtf(red[0]), 1e-8f);
  for(int i=t;i<HD;i+=256) xn[i] = x[i]/nrm;
}

// ----------------- sim + keys + hist (4 rows/block, 1/wave) -----------------
__global__ __launch_bounds__(256) void k_simkey(const float* __restrict__ mv, const float* __restrict__ xn,
                                                const float* __restrict__ surp, const float* __restrict__ noise,
                                                u32* __restrict__ keys3, u32* __restrict__ hist3){
  __shared__ float xs[HD];
  int t = threadIdx.x;
  for(int i=t;i<HD;i+=256) xs[i]=xn[i];
  __syncthreads();
  int lane = t & 63, w = t >> 6;
  int row = blockIdx.x*4 + w;
  const float4* p = (const float4*)(mv + (size_t)row*HD);
  const float4* q = (const float4*)xs;
  float d=0.f, ss=0.f;
  #pragma unroll
  for(int r=0;r<4;++r){
    float4 v = p[lane + 64*r]; float4 u = q[lane + 64*r];
    d  += v.x*u.x + v.y*u.y + v.z*u.z + v.w*u.w;
    ss += v.x*v.x + v.y*v.y + v.z*v.z + v.w*v.w;
  }
  for(int off=32;off>0;off>>=1){ d += __shfl_xor(d,off,64); ss += __shfl_xor(ss,off,64); }
  if(lane==0){
    float sim = d / fmaxf(sqrtf(ss),1e-8f);
    float vals[3] = { surp[row], sim, noise[row] };
    #pragma unroll
    for(int a=0;a<3;++a){
      u32 k = fkey(vals[a]);
      keys3[(size_t)a*NM + row] = k;
      atomicAdd(&hist3[(size_t)a*NBIN + (k >> 16)], 1u);
    }
  }
}

// ----------------- 3-stage parallel scan over 3x65536 bins -----------------
__global__ __launch_bounds__(256) void k_scanA(const u32* __restrict__ hist3, u32* __restrict__ bsum){
  __shared__ u32 red[256];
  int blk = blockIdx.x;                 // 192: a = blk>>6, chunk = blk&63
  int t = threadIdx.x;
  const u32* h = hist3 + (size_t)(blk>>6)*NBIN + (size_t)(blk&63)*1024;
  u32 s = 0;
  #pragma unroll
  for(int j=0;j<4;++j) s += h[t*4+j];
  red[t]=s; __syncthreads();
  for(int o=128;o>0;o>>=1){ if(t<o) red[t]+=red[t+o]; __syncthreads(); }
  if(t==0) bsum[blk] = red[0];
}

__global__ __launch_bounds__(256) void k_scanB(const u32* __restrict__ bsum, u32* __restrict__ bbase,
                                               u32* __restrict__ pref3){
  __shared__ u32 incl[256];
  int t = threadIdx.x;
  u32 v = (t < 192) ? bsum[t] : 0u;
  incl[t] = v; __syncthreads();
  for(int off=1;off<256;off<<=1){
    u32 u = (t >= off) ? incl[t-off] : 0u;
    __syncthreads(); incl[t] += u; __syncthreads();
  }
  if(t < 192){
    int a = t >> 6;
    u32 excl_t = incl[t] - v;
    u32 excl_a = incl[a*64] - bsum[a*64];
    bbase[t] = excl_t - excl_a;
  }
  if(t < 3) pref3[(size_t)t*(NBIN+1) + NBIN] = NM;
}

__global__ __launch_bounds__(256) void k_scanC(const u32* __restrict__ hist3, const u32* __restrict__ bbase,
                                               u32* __restrict__ pref3){
  __shared__ u32 part[256];
  int blk = blockIdx.x;
  int t = threadIdx.x;
  int a = blk >> 6, c = blk & 63;
  const u32* h = hist3 + (size_t)a*NBIN + (size_t)c*1024;
  u32* pref = pref3 + (size_t)a*(NBIN+1) + (size_t)c*1024;
  u32 loc[4]; u32 s = 0;
  #pragma unroll
  for(int j=0;j<4;++j){ loc[j] = h[t*4+j]; s += loc[j]; }
  part[t] = s; __syncthreads();
  for(int off=1;off<256;off<<=1){
    u32 u = (t >= off) ? part[t-off] : 0u;
    __syncthreads(); part[t] += u; __syncthreads();
  }
  u32 run = bbase[blk] + part[t] - s;
  #pragma unroll
  for(int j=0;j<4;++j){ pref[t*4+j] = run; run += loc[j]; }
}

// ----------------- scatter / rank+score -----------------
__global__ void k_scatter3(const u32* __restrict__ keys3, const u32* __restrict__ pref3,
                           u32* __restrict__ cnt3, u32* __restrict__ lo3){
  int i = blockIdx.x*256 + threadIdx.x;
  if(i >= NM) return;
  #pragma unroll
  for(int a=0;a<3;++a){
    u32 k = keys3[(size_t)a*NM + i];
    u32 b = k >> 16;
    u32 pos = pref3[(size_t)a*(NBIN+1) + b] + atomicAdd(&cnt3[(size_t)a*NBIN + b], 1u);
    lo3[(size_t)a*NM + pos] = k & 0xFFFFu;
  }
}

__global__ void k_rank3score(const u32* __restrict__ keys3, const u32* __restrict__ pref3,
                             const u32* __restrict__ lo3, u32* __restrict__ keysS, u32* __restrict__ histS){
  int i = blockIdx.x*256 + threadIdx.x;
  if(i >= NM) return;
  float rr[3];
  #pragma unroll
  for(int a=0;a<3;++a){
    u32 k = keys3[(size_t)a*NM + i];
    u32 b = k >> 16, my = k & 0xFFFFu;
    const u32* pref = pref3 + (size_t)a*(NBIN+1);
    const u32* lo = lo3 + (size_t)a*NM;
    u32 s = pref[b], e = pref[b+1];
    u32 nl = 0, ne = 0;
    for(u32 j=s;j<e;++j){ u32 u = lo[j]; nl += (u < my); ne += (u == my); }
    u32 left = s + nl, right = left + ne;
    rr[a] = (float)(left + right - 1) * (1.0f/131072.0f);
  }
  float sc = __fadd_rn(__fadd_rn(__fmul_rn(rr[0],rr[0]), __fmul_rn(rr[1],rr[1])), __fmul_rn(rr[2],rr[2]));
  u32 k = __float_as_uint(sc);
  keysS[i] = k;
  atomicAdd(&histS[k >> 16], 1u);
}

// ----------------- top-k -----------------
__global__ __launch_bounds__(1024) void k_sel1(const u32* __restrict__ hist, Ctrl* ctrl){
  __shared__ u32 part[1024];
  int t = threadIdx.x;
  u32 base = t*64, s = 0;
  for(int j=0;j<64;++j) s += hist[base+j];
  part[t] = s; __syncthreads();
  for(int off=1;off<1024;off<<=1){
    u32 v = (t+off < 1024) ? part[t+off] : 0u;
    __syncthreads(); part[t] += v; __syncthreads();
  }
  u32 above = part[t] - s;
  if(above < (u32)KS && above + s >= (u32)KS){
    u32 cum = above;
    for(int j=63;j>=0;--j){
      u32 c = hist[base+j];
      if(cum + c >= (u32)KS){ ctrl->T = (u32)(base+j) << 16; ctrl->candcnt = 0; break; }
      cum += c;
    }
  }
}

__global__ void k_collect(const u32* __restrict__ keys, Ctrl* ctrl, u64* __restrict__ cand){
  int i = blockIdx.x*256 + threadIdx.x;
  if(i >= NM) return;
  u32 k = keys[i];
  if(k >= ctrl->T){
    u32 p = atomicAdd(&ctrl->candcnt, 1u);
    if(p < (u32)CCAP) cand[p] = ((u64)(~k) << 32) | (u32)i;
  }
}

__global__ __launch_bounds__(1024) void k_sortsel(const u64* __restrict__ cand, const Ctrl* ctrl, int* __restrict__ idx){
  __shared__ u64 sm[CCAP];
  int t = threadIdx.x;
  u32 n = ctrl->candcnt; if(n > (u32)CCAP) n = CCAP;
  for(int i=t;i<CCAP;i+=1024) sm[i] = (i < (int)n) ? cand[i] : 0xFFFFFFFFFFFFFFFFull;
  __syncthreads();
  for(int k=2;k<=CCAP;k<<=1){
    for(int j=k>>1;j>0;j>>=1){
      for(int i=t;i<CCAP;i+=1024){
        int ixj = i ^ j;
        if(ixj > i){
          bool up = ((i & k) == 0);
          u64 a = sm[i], b = sm[ixj];
          if((a > b) == up){ sm[i] = b; sm[ixj] = a; }
        }
      }
      __syncthreads();
    }
  }
  if(t < KS) idx[t] = (int)(sm[t] & 0xFFFFFFFFu);
}

// ----------------- gather -----------------
__global__ void k_gather(const int* __restrict__ idx,
                         const float* __restrict__ mv, const float* __restrict__ mnv,
                         const float* __restrict__ mrew,
                         const int* __restrict__ aim, const int* __restrict__ ait,
                         const float* __restrict__ amw1, const float* __restrict__ amb1,
                         const float* __restrict__ atw1, const float* __restrict__ atb1,
                         const float* __restrict__ start, const float* __restrict__ x,
                         const float* __restrict__ pos,
                         float* __restrict__ vecs, float* __restrict__ outnext,
                         float* __restrict__ hm, float* __restrict__ ht,
                         float* __restrict__ rew, float* __restrict__ outrew){
  int k = blockIdx.x;
  int t = threadIdx.x;
  if(k < KS){
    int row = idx[k];
    const float* a = mv  + (size_t)row*HD;
    const float* b = mnv + (size_t)row*HD;
    const float* pz = pos + (size_t)(2*k+1)*HD;
    float* vr = vecs + (size_t)(2*k+1)*HD;
    for(int c=t;c<HD;c+=256){
      vr[c] = a[c] + pz[c];
      outnext[(size_t)k*HD+c] = b[c];
    }
    int am = aim[row], at = ait[row];
    for(int j=t;j<HD;j+=256){
      hm[(size_t)k*HD+j] = gelu_f(amw1[(size_t)j*9 + am] + amb1[j]);
      ht[(size_t)k*HD+j] = gelu_f(atw1[(size_t)j*4 + at] + atb1[j]);
    }
    if(t == 0){ float r = mrew[row]; rew[k] = r; outrew[k] = r; }
  } else {
    for(int c=t;c<HD;c+=256){
      vecs[c] = start[c] + pos[c];
      vecs[(size_t)(SQ-1)*HD + c] = x[c] + pos[(size_t)(SQ-1)*HD + c];
    }
  }
}

// ----------------- bf16 MFMA split-K GEMM body (partials only) -----------------
__device__ __forceinline__ void gemm_body(char* smem, const float* __restrict__ A, const float* __restrict__ B,
        float* __restrict__ P, int M, int N, int K, int S, int nbm, int lda, int tile){
  short* As = (short*)smem;
  short* Bs = (short*)(smem + 8192);
  int bm = (tile % nbm) * 64;
  int tmp = tile / nbm;
  int z  = tmp % S;
  int bn = (tmp / S) * 64;
  int Ks = K / S, kbeg = z*Ks;
  int nk = Ks >> 5;

  int t = threadIdx.x;
  int srow = t >> 2, sg = t & 3;
  int sgp = sg ^ ((srow >> 1) & 3);
  bool arow_ok = (bm + srow) < M;
  const float* ap = A + (size_t)(bm + srow)*lda + kbeg + sg*8;
  const float* bp = B + (size_t)(bn + srow)*K + kbeg + sg*8;
  int stoff = srow*32 + sgp*8;

  int lane = t & 63, w = t >> 6;
  int wm = (w >> 1)*32, wn = (w & 1)*32;
  int lr = lane & 15, lg = lane >> 4;
  int ra0 = wm + lr, ra1 = ra0 + 16;
  int rb0 = wn + lr, rb1 = rb0 + 16;
  int aoff0 = ra0*32 + (lg ^ ((ra0>>1)&3))*8;
  int aoff1 = ra1*32 + (lg ^ ((ra1>>1)&3))*8;
  int boff0 = rb0*32 + (lg ^ ((rb0>>1)&3))*8;
  int boff1 = rb1*32 + (lg ^ ((rb1>>1)&3))*8;

  f32x4v acc00 = {0,0,0,0}, acc01 = {0,0,0,0}, acc10 = {0,0,0,0}, acc11 = {0,0,0,0};

  {
    float4 va0 = {0,0,0,0}, va1 = {0,0,0,0};
    if(arow_ok){ va0 = *(const float4*)ap; va1 = *(const float4*)(ap+4); }
    float4 vb0 = *(const float4*)bp;
    float4 vb1 = *(const float4*)(bp+4);
    ap += 32; bp += 32;
    bf16x8 sa, sb;
    sa[0]=f2bf(va0.x); sa[1]=f2bf(va0.y); sa[2]=f2bf(va0.z); sa[3]=f2bf(va0.w);
    sa[4]=f2bf(va1.x); sa[5]=f2bf(va1.y); sa[6]=f2bf(va1.z); sa[7]=f2bf(va1.w);
    sb[0]=f2bf(vb0.x); sb[1]=f2bf(vb0.y); sb[2]=f2bf(vb0.z); sb[3]=f2bf(vb0.w);
    sb[4]=f2bf(vb1.x); sb[5]=f2bf(vb1.y); sb[6]=f2bf(vb1.z); sb[7]=f2bf(vb1.w);
    *(bf16x8*)&As[stoff] = sa;
    *(bf16x8*)&Bs[stoff] = sb;
  }
  __syncthreads();

  for(int kk = 0; kk < nk; ++kk){
    int cur = (kk & 1) << 11;
    bool more = (kk + 1) < nk;
    float4 va0, va1, vb0, vb1;
    if(more){
      va0 = make_float4(0,0,0,0); va1 = make_float4(0,0,0,0);
      if(arow_ok){ va0 = *(const float4*)ap; va1 = *(const float4*)(ap+4); }
      vb0 = *(const float4*)bp;
      vb1 = *(const float4*)(bp+4);
      ap += 32; bp += 32;
    }
    bf16x8 a0 = *(const bf16x8*)&As[cur + aoff0];
    bf16x8 a1 = *(const bf16x8*)&As[cur + aoff1];
    bf16x8 b0 = *(const bf16x8*)&Bs[cur + boff0];
    bf16x8 b1 = *(const bf16x8*)&Bs[cur + boff1];
    acc00 = __builtin_amdgcn_mfma_f32_16x16x32_bf16(a0, b0, acc00, 0, 0, 0);
    acc01 = __builtin_amdgcn_mfma_f32_16x16x32_bf16(a0, b1, acc01, 0, 0, 0);
    acc10 = __builtin_amdgcn_mfma_f32_16x16x32_bf16(a1, b0, acc10, 0, 0, 0);
    acc11 = __builtin_amdgcn_mfma_f32_16x16x32_bf16(a1, b1, acc11, 0, 0, 0);
    if(more){
      int nxt = cur ^ 2048;
      bf16x8 sa, sb;
      sa[0]=f2bf(va0.x); sa[1]=f2bf(va0.y); sa[2]=f2bf(va0.z); sa[3]=f2bf(va0.w);
      sa[4]=f2bf(va1.x); sa[5]=f2bf(va1.y); sa[6]=f2bf(va1.z); sa[7]=f2bf(va1.w);
      sb[0]=f2bf(vb0.x); sb[1]=f2bf(vb0.y); sb[2]=f2bf(vb0.z); sb[3]=f2bf(vb0.w);
      sb[4]=f2bf(vb1.x); sb[5]=f2bf(vb1.y); sb[6]=f2bf(vb1.z); sb[7]=f2bf(vb1.w);
      *(bf16x8*)&As[nxt + stoff] = sa;
      *(bf16x8*)&Bs[nxt + stoff] = sb;
    }
    __syncthreads();
  }

  size_t zbase = (size_t)z * (size_t)M;
  #pragma unroll
  for(int r=0;r<4;++r){
    int row0 = bm + wm + lg*4 + r;
    int row1 = row0 + 16;
    int c0 = bn + wn + lr, c1 = c0 + 16;
    if(row0 < M){
      P[(zbase+row0)*N + c0] = acc00[r];
      P[(zbase+row0)*N + c1] = acc01[r];
    }
    if(row1 < M){
      P[(zbase+row1)*N + c0] = acc10[r];
      P[(zbase+row1)*N + c1] = acc11[r];
    }
  }
}

__global__ __launch_bounds__(256) void k_gemm(const float* __restrict__ A, const float* __restrict__ B,
        float* __restrict__ P, int M, int N, int K, int S, int nbm, int lda){
  __shared__ char smem[16384];
  u32 nwg = gridDim.x, orig = blockIdx.x;
  u32 swz = (orig & 7)*(nwg >> 3) + (orig >> 3);   // nwg % 8 == 0 always here
  gemm_body(smem, A, B, P, M, N, K, S, nbm, lda, (int)swz);
}

__global__ __launch_bounds__(256) void k_actgemm(const float* __restrict__ hm, const float* __restrict__ ht,
        const float* __restrict__ amw2, const float* __restrict__ atw2,
        float* __restrict__ part, float* __restrict__ part2){
  __shared__ char smem[16384];
  int which = blockIdx.x >> 8, tile = blockIdx.x & 255;   // 2x16 tiles x S8 = 256 each
  gemm_body(smem, which ? ht : hm, which ? atw2 : amw2, which ? part2 : part,
            KS, HD, HD, 8, 2, HD, tile);
}

// ----------------- flat epilogue: sum S_ slices + bias (+gelu) -----------------
template<int S_, int ACT>
__global__ __launch_bounds__(256) void k_finS(const float* __restrict__ P, const float* __restrict__ bias,
                                              float* __restrict__ C, int MN4, int Nd){
  int i4 = blockIdx.x*256 + threadIdx.x;
  if(i4 >= MN4) return;
  size_t off = (size_t)i4*4;
  size_t MN = (size_t)MN4*4;
  float4 v = *(const float4*)&P[off];
  #pragma unroll
  for(int z=1;z<S_;++z){
    float4 q = *(const float4*)&P[(size_t)z*MN + off];
    v.x += q.x; v.y += q.y; v.z += q.z; v.w += q.w;
  }
  int j = (i4 % (Nd/4))*4;
  float4 b4 = *(const float4*)&bias[j];
  v.x += b4.x; v.y += b4.y; v.z += b4.z; v.w += b4.w;
  if(ACT == 1){ v.x = gelu_f(v.x); v.y = gelu_f(v.y); v.z = gelu_f(v.z); v.w = gelu_f(v.w); }
  *(float4*)&C[off] = v;
}

// ----------------- row finish: sum S_ slices + bias + residual (+LN | copy-out) -----------------
template<int S_, bool LN>
__global__ __launch_bounds__(256) void k_finrow(const float* __restrict__ P, const float* __restrict__ bias,
                                                float* __restrict__ vecs, const float* __restrict__ lw,
                                                const float* __restrict__ lb, float* __restrict__ dst){
  __shared__ float red[256];
  int row = blockIdx.x, t = threadIdx.x;
  int j = t*4;
  float4 v = *(const float4*)&P[(size_t)row*HD + j];
  #pragma unroll
  for(int z=1;z<S_;++z){
    float4 p = *(const float4*)&P[((size_t)z*SQ + row)*HD + j];
    v.x += p.x; v.y += p.y; v.z += p.z; v.w += p.w;
  }
  float4 b4 = *(const float4*)&bias[j];
  float4 r4 = *(const float4*)&vecs[(size_t)row*HD + j];
  v.x += b4.x + r4.x; v.y += b4.y + r4.y; v.z += b4.z + r4.z; v.w += b4.w + r4.w;
  *(float4*)&vecs[(size_t)row*HD + j] = v;
  if(LN){
    red[t] = v.x+v.y+v.z+v.w; __syncthreads();
    for(int o=128;o>0;o>>=1){ if(t<o) red[t]+=red[t+o]; __syncthreads(); }
    float m = red[0]*(1.0f/HD); __syncthreads();
    float dx=v.x-m, dy=v.y-m, dz=v.z-m, dw=v.w-m;
    red[t] = dx*dx+dy*dy+dz*dz+dw*dw; __syncthreads();
    for(int o=128;o>0;o>>=1){ if(t<o) red[t]+=red[t+o]; __syncthreads(); }
    float den = sqrtf(red[0]*(1.0f/HD) + 1e-5f);
    float4 w4 = *(const float4*)&lw[j];
    float4 lb4 = *(const float4*)&lb[j];
    float4 o4;
    o4.x = dx/den*w4.x + lb4.x; o4.y = dy/den*w4.y + lb4.y;
    o4.z = dz/den*w4.z + lb4.z; o4.w = dw/den*w4.w + lb4.w;
    *(float4*)&dst[(size_t)row*HD + j] = o4;
  } else {
    if(row >= 1) *(float4*)&dst[(size_t)(row-1)*HD + j] = v;
  }
}

// ----------------- finav (even rows from 8-slice action partials) + LN1 all rows -----------------
__global__ __launch_bounds__(256) void k_finavln(const float* __restrict__ Pm, const float* __restrict__ Pt,
                                                 const float* __restrict__ bm_, const float* __restrict__ bt_,
                                                 const float* __restrict__ pos, float* __restrict__ vecs,
                                                 const float* __restrict__ lw, const float* __restrict__ lb,
                                                 float* __restrict__ lnb){
  __shared__ float red[256];
  int row = blockIdx.x, t = threadIdx.x;
  int j = t*4;
  float4 v;
  if(row >= 2 && row <= 256 && ((row & 1) == 0)){
    int k = (row-2) >> 1;
    float4 s = {0,0,0,0};
    #pragma unroll
    for(int z=0;z<8;++z){
      float4 a = *(const float4*)&Pm[((size_t)z*KS + k)*HD + j];
      float4 b = *(const float4*)&Pt[((size_t)z*KS + k)*HD + j];
      s.x += a.x+b.x; s.y += a.y+b.y; s.z += a.z+b.z; s.w += a.w+b.w;
    }
    float4 bm4 = *(const float4*)&bm_[j];
    float4 bt4 = *(const float4*)&bt_[j];
    float4 p4 = *(const float4*)&pos[(size_t)row*HD + j];
    v.x = 0.5f*(s.x + bm4.x + bt4.x) + p4.x;
    v.y = 0.5f*(s.y + bm4.y + bt4.y) + p4.y;
    v.z = 0.5f*(s.z + bm4.z + bt4.z) + p4.z;
    v.w = 0.5f*(s.w + bm4.w + bt4.w) + p4.w;
    *(float4*)&vecs[(size_t)row*HD + j] = v;
  } else {
    v = *(const float4*)&vecs[(size_t)row*HD + j];
  }
  red[t] = v.x+v.y+v.z+v.w; __syncthreads();
  for(int o=128;o>0;o>>=1){ if(t<o) red[t]+=red[t+o]; __syncthreads(); }
  float m = red[0]*(1.0f/HD); __syncthreads();
  float dx=v.x-m, dy=v.y-m, dz=v.z-m, dw=v.w-m;
  red[t] = dx*dx+dy*dy+dz*dz+dw*dw; __syncthreads();
  for(int o=128;o>0;o>>=1){ if(t<o) red[t]+=red[t+o]; __syncthreads(); }
  float den = sqrtf(red[0]*(1.0f/HD) + 1e-5f);
  float4 w4 = *(const float4*)&lw[j];
  float4 lb4 = *(const float4*)&lb[j];
  float4 o4;
  o4.x = dx/den*w4.x + lb4.x; o4.y = dy/den*w4.y + lb4.y;
  o4.z = dz/den*w4.z + lb4.z; o4.w = dw/den*w4.w + lb4.w;
  *(float4*)&lnb[(size_t)row*HD + j] = o4;
}

// ----------------- attention -----------------
__global__ void k_attn(const float* __restrict__ qkv, float* __restrict__ outp){
  __shared__ float qv[64];
  __shared__ float p[SQ];
  __shared__ float red[256];
  int q = blockIdx.x, h = blockIdx.y, t = threadIdx.x;
  if(t < 64) qv[t] = qkv[(size_t)q*3072 + h*64 + t];
  __syncthreads();
  int nk = q + 1;
  float lmax = -1e30f;
  for(int j=t;j<nk;j+=256){
    const float* kr = qkv + (size_t)j*3072 + 1024 + h*64;
    float d = 0.f;
    for(int c=0;c<64;++c) d += qv[c]*kr[c];
    d *= 0.125f;
    p[j] = d;
    lmax = fmaxf(lmax, d);
  }
  red[t] = lmax; __syncthreads();
  for(int o=128;o>0;o>>=1){ if(t<o) red[t] = fmaxf(red[t], red[t+o]); __syncthreads(); }
  float m = red[0];
  __syncthreads();
  float lsum = 0.f;
  for(int j=t;j<nk;j+=256){ float e = expf(p[j]-m); p[j] = e; lsum += e; }
  red[t] = lsum; __syncthreads();
  for(int o=128;o>0;o>>=1){ if(t<o) red[t] += red[t+o]; __syncthreads(); }
  float inv = 1.0f/red[0];
  __syncthreads();
  int d = t & 63, g = t >> 6;
  float acc = 0.f;
  for(int j=g;j<nk;j+=4) acc += p[j]*qkv[(size_t)j*3072 + 2048 + h*64 + d];
  red[t] = acc; __syncthreads();
  if(g == 0){
    float o4 = red[d] + red[64+d] + red[128+d] + red[192+d];
    outp[(size_t)q*HD + h*64 + d] = o4*inv;
  }
}

// ----------------- value head finish: sum 4 slices + bias, gelu, dot w2 -----------------
__global__ __launch_bounds__(256) void k_vpfin(const float* __restrict__ P, const float* __restrict__ vb1,
                                               const float* __restrict__ vw2, float* __restrict__ vp){
  __shared__ float red[256];
  int r = blockIdx.x, t = threadIdx.x;
  float s = 0.f;
  for(int c=t;c<4096;c+=256){
    float v = P[(size_t)r*4096 + c];
    #pragma unroll
    for(int z=1;z<4;++z) v += P[((size_t)z*129 + r)*4096 + c];
    s += gelu_f(v + vb1[c]) * vw2[c];
  }
  red[t]=s; __syncthreads();
  for(int o=128;o>0;o>>=1){ if(t<o) red[t]+=red[t+o]; __syncthreads(); }
  if(t == 0) vp[r] = red[0];
}

__global__ void k_outsmall(const float* __restrict__ vp, const float* __restrict__ b2,
                           const float* __restrict__ rew, float* __restrict__ outp){
  int t = threadIdx.x;
  float bb = b2[0];
  if(t == 0) outp[OUT_VP] = vp[KS] + bb;
  if(t < KS){
    float d = (vp[t] + bb) - rew[t];
    outp[OUT_LOSS + t] = d*d;
    outp[OUT_REWO + t] = rew[t];
  }
}

extern "C" void kernel_launch(void* const* d_in, const int* in_sizes, int n_in,
                              void* d_out, int out_size, void* d_ws, size_t ws_size,
                              hipStream_t stream){
  const float* x     = (const float*)d_in[0];
  const float* mv    = (const float*)d_in[1];
  const float* mnv   = (const float*)d_in[2];
  const float* surp  = (const float*)d_in[3];
  const float* mrew  = (const float*)d_in[4];
  const float* noise = (const float*)d_in[5];
  const int*   aim   = (const int*)d_in[6];
  const int*   ait   = (const int*)d_in[7];
  const float* start = (const float*)d_in[8];
  const float* pos   = (const float*)d_in[9];
  const float* inW = (const float*)d_in[10]; const float* inB = (const float*)d_in[11];
  const float* oW  = (const float*)d_in[12]; const float* oB  = (const float*)d_in[13];
  const float* l1w = (const float*)d_in[14]; const float* l1b = (const float*)d_in[15];
  const float* l2w = (const float*)d_in[16]; const float* l2b = (const float*)d_in[17];
  const float* f1w = (const float*)d_in[18]; const float* f1b = (const float*)d_in[19];
  const float* f2w = (const float*)d_in[20]; const float* f2b = (const float*)d_in[21];
  const float* amw1= (const float*)d_in[22]; const float* amb1= (const float*)d_in[23];
  const float* amw2= (const float*)d_in[24]; const float* amb2= (const float*)d_in[25];
  const float* atw1= (const float*)d_in[26]; const float* atb1= (const float*)d_in[27];
  const float* atw2= (const float*)d_in[28]; const float* atb2= (const float*)d_in[29];
  const float* vw1 = (const float*)d_in[30]; const float* vb1 = (const float*)d_in[31];
  const float* vw2 = (const float*)d_in[32]; const float* vb2 = (const float*)d_in[33];

  float* out = (float*)d_out;
  char* ws = (char*)d_ws;
  u32*  hist3 = (u32*)(ws+OFF_H3);
  u32*  cnt3  = (u32*)(ws+OFF_C3);
  u32*  histS = (u32*)(ws+OFF_HS);
  u32*  bsum  = (u32*)(ws+OFF_BS);
  u32*  bbase = (u32*)(ws+OFF_BB);
  float* vp   = (float*)(ws+OFF_VPB);
  float* xn   = (float*)(ws+OFF_XN);
  u32*  pref3 = (u32*)(ws+OFF_P3);
  u32*  keys3 = (u32*)(ws+OFF_K3);
  u32*  lo3   = (u32*)(ws+OFF_L3);
  u32*  keysS = (u32*)(ws+OFF_KSC);
  u64*  cand  = (u64*)(ws+OFF_CAND);
  Ctrl* ctrl  = (Ctrl*)(ws+OFF_CTRL);
  int*  idxb  = (int*)(ws+OFF_IDX);
  float* hm   = (float*)(ws+OFF_HM);
  float* ht   = (float*)(ws+OFF_HT);
  float* rew  = (float*)(ws+OFF_REW);
  float* vecs = (float*)(ws+OFF_VECS);
  float* lnb  = (float*)(ws+OFF_LNB);
  float* qkvb = (float*)(ws+OFF_QKV);
  float* attn = (float*)(ws+OFF_ATT);
  float* ffh  = (float*)(ws+OFF_FFH);
  float* part = (float*)(ws+OFF_PART);
  float* part2= part + (size_t)8*KS*HD;

  dim3 b256(256);
  int gN = NM/256;

  (void)hipMemsetAsync(ws, 0, ZERO_BYTES, stream);

  // ---- scoring / ranking / top-k ----
  hipLaunchKernelGGL(k_xn, dim3(1), b256, 0, stream, x, xn);
  hipLaunchKernelGGL(k_simkey, dim3(NM/4), b256, 0, stream, mv, xn, surp, noise, keys3, hist3);
  hipLaunchKernelGGL(k_scanA, dim3(192), b256, 0, stream, hist3, bsum);
  hipLaunchKernelGGL(k_scanB, dim3(1), b256, 0, stream, bsum, bbase, pref3);
  hipLaunchKernelGGL(k_scanC, dim3(192), b256, 0, stream, hist3, bbase, pref3);
  hipLaunchKernelGGL(k_scatter3, dim3(gN), b256, 0, stream, keys3, pref3, cnt3, lo3);
  hipLaunchKernelGGL(k_rank3score, dim3(gN), b256, 0, stream, keys3, pref3, lo3, keysS, histS);
  hipLaunchKernelGGL(k_sel1, dim3(1), dim3(1024), 0, stream, histS, ctrl);
  hipLaunchKernelGGL(k_collect, dim3(gN), b256, 0, stream, keysS, ctrl, cand);
  hipLaunchKernelGGL(k_sortsel, dim3(1), dim3(1024), 0, stream, cand, ctrl, idxb);

  // ---- gather + action MLPs + assembly/LN1 ----
  hipLaunchKernelGGL(k_gather, dim3(KS+1), b256, 0, stream, idxb, mv, mnv, mrew, aim, ait,
                     amw1, amb1, atw1, atb1, start, x, pos,
                     vecs, out + OUT_NEXT, hm, ht, rew, out + OUT_REWO);
  hipLaunchKernelGGL(k_actgemm, dim3(512), b256, 0, stream, hm, ht, amw2, atw2, part, part2);
  hipLaunchKernelGGL(k_finavln, dim3(SQ), b256, 0, stream, part, part2, amb2, atb2, pos, vecs, l1w, l1b, lnb);

  // ---- transformer ----
  for(int l=0;l<NL;++l){
    // qkv: S=2, 480 blocks -> partials; epilogue 774 blocks
    hipLaunchKernelGGL(k_gemm, dim3(480), b256, 0, stream, lnb, inW + (size_t)l*3*HD*HD, part, SQ, 3*HD, HD, 2, 5, HD);
    hipLaunchKernelGGL((k_finS<2,0>), dim3(774), b256, 0, stream, part, inB + (size_t)l*3*HD, qkvb, SQ*3*HD/4, 3*HD);
    hipLaunchKernelGGL(k_attn, dim3(SQ, 16), b256, 0, stream, qkvb, attn);
    // o-proj: S=8, 640 blocks
    hipLaunchKernelGGL(k_gemm, dim3(640), b256, 0, stream, attn, oW + (size_t)l*HD*HD, part, SQ, HD, HD, 8, 5, HD);
    hipLaunchKernelGGL((k_finrow<8,true>), dim3(SQ), b256, 0, stream, part, oB + (size_t)l*HD, vecs,
                       l2w + (size_t)l*HD, l2b + (size_t)l*HD, lnb);
    // ffn1: S=2, 640 blocks; gelu epilogue 1032 blocks
    hipLaunchKernelGGL(k_gemm, dim3(640), b256, 0, stream, lnb, f1w + (size_t)l*4*HD*HD, part, SQ, 4*HD, HD, 2, 5, HD);
    hipLaunchKernelGGL((k_finS<2,1>), dim3(1032), b256, 0, stream, part, f1b + (size_t)l*4*HD, ffh, SQ*4*HD/4, 4*HD);
    // ffn2: S=8, 640 blocks
    hipLaunchKernelGGL(k_gemm, dim3(640), b256, 0, stream, ffh, f2w + (size_t)l*HD*4*HD, part, SQ, HD, 4*HD, 8, 5, 4*HD);
    if(l < NL-1)
      hipLaunchKernelGGL((k_finrow<8,true>), dim3(SQ), b256, 0, stream, part, f2b + (size_t)l*HD, vecs,
                         l1w + (size_t)(l+1)*HD, l1b + (size_t)(l+1)*HD, lnb);
    else
      hipLaunchKernelGGL((k_finrow<8,false>), dim3(SQ), b256, 0, stream, part, f2b + (size_t)l*HD, vecs,
                         (const float*)nullptr, (const float*)nullptr, out);
  }

  // ---- value head: S=4, 768 blocks; finish 129 blocks ----
  hipLaunchKernelGGL(k_gemm, dim3(768), b256, 0, stream, vecs + HD, vw1, part, KS+1, 4*HD, HD, 4, 3, 2*HD);
  hipLaunchKernelGGL(k_vpfin, dim3(KS+1), b256, 0, stream, part, vb1, vw2, vp);
  hipLaunchKernelGGL(k_outsmall, dim3(1), b256, 0, stream, vp, vb2, rew, out);
}

// Round 8
// 947.477 us; speedup vs baseline: 2.9913x; 1.0267x over previous
//
#include <hip/hip_runtime.h>
#include <hip/hip_bf16.h>
#include <math.h>
#include <stdint.h>

typedef unsigned int u32;
typedef unsigned short u16;
typedef unsigned long long u64;

#define NM   65536
#define HD   1024
#define KS   128
#define SQ   258
#define NL   4
#define NBIN 65536
#define CCAP 2048

using bf16x8 = __attribute__((ext_vector_type(8))) short;
using f32x4v = __attribute__((ext_vector_type(4))) float;

struct Ctrl { u32 b1, above1, T, candcnt; };

static constexpr size_t A256(size_t x){ return (x + 255) & ~(size_t)255; }

// ---- zeroed-at-launch region (ONE memset) ----
constexpr size_t OFF_H3   = 0;                                  // 3*NBIN u32
constexpr size_t OFF_C3   = OFF_H3 + (size_t)3*NBIN*4;          // 3*NBIN u32
constexpr size_t OFF_HS   = OFF_C3 + (size_t)3*NBIN*4;          // NBIN u32
constexpr size_t ZERO_BYTES = OFF_HS + (size_t)NBIN*4;
// ---- rest ----
constexpr size_t OFF_BS   = A256(ZERO_BYTES);
constexpr size_t OFF_BB   = A256(OFF_BS + 192*4);
constexpr size_t OFF_VPB  = A256(OFF_BB + 192*4);
constexpr size_t OFF_XN   = A256(OFF_VPB + 1024);
constexpr size_t OFF_P3   = A256(OFF_XN + (size_t)HD*4);
constexpr size_t OFF_K3   = A256(OFF_P3 + (size_t)3*(NBIN+1)*4);
constexpr size_t OFF_L3   = A256(OFF_K3 + (size_t)3*NM*4);
constexpr size_t OFF_KSC  = A256(OFF_L3 + (size_t)3*NM*4);
constexpr size_t OFF_CAND = A256(OFF_KSC + (size_t)NM*4);
constexpr size_t OFF_CTRL = A256(OFF_CAND + (size_t)CCAP*8);
constexpr size_t OFF_IDX  = A256(OFF_CTRL + 256);
constexpr size_t OFF_REW  = A256(OFF_IDX  + (size_t)KS*4);
constexpr size_t OFF_HM   = A256(OFF_REW  + (size_t)KS*4);            // u16 [128][1024]
constexpr size_t OFF_HT   = A256(OFF_HM   + (size_t)KS*HD*2);         // u16
constexpr size_t OFF_VECS = A256(OFF_HT   + (size_t)KS*HD*2);         // f32 [258][1024]
constexpr size_t OFF_LNB  = A256(OFF_VECS + (size_t)SQ*HD*4);         // u16 [258][1024]
constexpr size_t OFF_QKV  = A256(OFF_LNB  + (size_t)SQ*HD*2);         // f32 [258][3072]
constexpr size_t OFF_ATT  = A256(OFF_QKV  + (size_t)SQ*3*HD*4);       // u16 [258][1024]
constexpr size_t OFF_FFH  = A256(OFF_ATT  + (size_t)SQ*HD*2);         // u16 [258][4096]
constexpr size_t OFF_VHIN = A256(OFF_FFH  + (size_t)SQ*4*HD*2);       // u16 [129][1024]
constexpr size_t OFF_WB   = A256(OFF_VHIN + (size_t)129*HD*2);        // u16 weights 56623104
constexpr size_t NWELEM   = 56623104;
constexpr size_t OFF_PART = A256(OFF_WB + NWELEM*2);                  // f32 partials

// bf16 weight sub-offsets (u16 elems)
constexpr size_t WB_IN = 0;
constexpr size_t WB_O  = WB_IN + (size_t)4*3*HD*HD;
constexpr size_t WB_F1 = WB_O  + (size_t)4*HD*HD;
constexpr size_t WB_F2 = WB_F1 + (size_t)4*4*HD*HD;
constexpr size_t WB_AM = WB_F2 + (size_t)4*4*HD*HD;
constexpr size_t WB_AT = WB_AM + (size_t)HD*HD;
constexpr size_t WB_VH = WB_AT + (size_t)HD*HD;

// output layout (floats)
constexpr int OUT_NEXT = 257*HD;
constexpr int OUT_VP   = OUT_NEXT + KS*HD;
constexpr int OUT_LOSS = OUT_VP + 1;
constexpr int OUT_REWO = OUT_LOSS + KS;

__device__ __forceinline__ float gelu_f(float v){
  return 0.5f*v*(1.0f + erff(v*0.70710678118654752440f));
}

__device__ __forceinline__ u16 f2bf(float f){
  __hip_bfloat16 h = __float2bfloat16(f);
  u16 s;
  __builtin_memcpy(&s, &h, sizeof(u16));
  return s;
}

__device__ __forceinline__ u32 fkey(float v){
  u32 b = __float_as_uint(v);
  return (b >> 31) ? ~b : (b | 0x80000000u);
}

__device__ __forceinline__ void gload16(const u16* g, u16* l){
  __builtin_amdgcn_global_load_lds(
      (const __attribute__((address_space(1))) unsigned int*)g,
      (__attribute__((address_space(3))) unsigned int*)l, 16, 0, 0);
}

// ----------------- weight conversion fp32 -> bf16 -----------------
struct WSeg { const float* s; u16* d; u32 base4, end4; };
struct WCA { WSeg seg[7]; u32 tot4; };
__global__ __launch_bounds__(256) void k_wconv(WCA a){
  u32 i = blockIdx.x*256 + threadIdx.x;
  if(i >= a.tot4) return;
  #pragma unroll
  for(int j=0;j<7;++j){
    if(i < a.seg[j].end4){
      u32 off = i - a.seg[j].base4;
      float4 v = *(const float4*)&a.seg[j].s[(size_t)off*4];
      u16 r[4] = { f2bf(v.x), f2bf(v.y), f2bf(v.z), f2bf(v.w) };
      u64 pk; __builtin_memcpy(&pk, r, 8);
      *(u64*)&a.seg[j].d[(size_t)off*4] = pk;
      return;
    }
  }
}

// ----------------- xn (once) -----------------
__global__ void k_xn(const float* __restrict__ x, float* __restrict__ xn){
  __shared__ float red[256];
  int t = threadIdx.x;
  float s = 0.f;
  for(int i=t;i<HD;i+=256){ float v=x[i]; s += v*v; }
  red[t]=s; __syncthreads();
  for(int o=128;o>0;o>>=1){ if(t<o) red[t]+=red[t+o]; __syncthreads(); }
  float nrm = fmaxf(sqrtf(red[0]), 1e-8f);
  for(int i=t;i<HD;i+=256) xn[i] = x[i]/nrm;
}

// ----------------- sim + keys + hist -----------------
__global__ __launch_bounds__(256) void k_simkey(const float* __restrict__ mv, const float* __restrict__ xn,
                                                const float* __restrict__ surp, const float* __restrict__ noise,
                                                u32* __restrict__ keys3, u32* __restrict__ hist3){
  __shared__ float xs[HD];
  int t = threadIdx.x;
  for(int i=t;i<HD;i+=256) xs[i]=xn[i];
  __syncthreads();
  int lane = t & 63, w = t >> 6;
  int row = blockIdx.x*4 + w;
  const float4* p = (const float4*)(mv + (size_t)row*HD);
  const float4* q = (const float4*)xs;
  float d=0.f, ss=0.f;
  #pragma unroll
  for(int r=0;r<4;++r){
    float4 v = p[lane + 64*r]; float4 u = q[lane + 64*r];
    d  += v.x*u.x + v.y*u.y + v.z*u.z + v.w*u.w;
    ss += v.x*v.x + v.y*v.y + v.z*v.z + v.w*v.w;
  }
  for(int off=32;off>0;off>>=1){ d += __shfl_xor(d,off,64); ss += __shfl_xor(ss,off,64); }
  if(lane==0){
    float sim = d / fmaxf(sqrtf(ss),1e-8f);
    float vals[3] = { surp[row], sim, noise[row] };
    #pragma unroll
    for(int a=0;a<3;++a){
      u32 k = fkey(vals[a]);
      keys3[(size_t)a*NM + row] = k;
      atomicAdd(&hist3[(size_t)a*NBIN + (k >> 16)], 1u);
    }
  }
}

// ----------------- 3-stage parallel scan -----------------
__global__ __launch_bounds__(256) void k_scanA(const u32* __restrict__ hist3, u32* __restrict__ bsum){
  __shared__ u32 red[256];
  int blk = blockIdx.x;
  int t = threadIdx.x;
  const u32* h = hist3 + (size_t)(blk>>6)*NBIN + (size_t)(blk&63)*1024;
  u32 s = 0;
  #pragma unroll
  for(int j=0;j<4;++j) s += h[t*4+j];
  red[t]=s; __syncthreads();
  for(int o=128;o>0;o>>=1){ if(t<o) red[t]+=red[t+o]; __syncthreads(); }
  if(t==0) bsum[blk] = red[0];
}

__global__ __launch_bounds__(256) void k_scanB(const u32* __restrict__ bsum, u32* __restrict__ bbase,
                                               u32* __restrict__ pref3){
  __shared__ u32 incl[256];
  int t = threadIdx.x;
  u32 v = (t < 192) ? bsum[t] : 0u;
  incl[t] = v; __syncthreads();
  for(int off=1;off<256;off<<=1){
    u32 u = (t >= off) ? incl[t-off] : 0u;
    __syncthreads(); incl[t] += u; __syncthreads();
  }
  if(t < 192){
    int a = t >> 6;
    u32 excl_t = incl[t] - v;
    u32 excl_a = incl[a*64] - bsum[a*64];
    bbase[t] = excl_t - excl_a;
  }
  if(t < 3) pref3[(size_t)t*(NBIN+1) + NBIN] = NM;
}

__global__ __launch_bounds__(256) void k_scanC(const u32* __restrict__ hist3, const u32* __restrict__ bbase,
                                               u32* __restrict__ pref3){
  __shared__ u32 part[256];
  int blk = blockIdx.x;
  int t = threadIdx.x;
  int a = blk >> 6, c = blk & 63;
  const u32* h = hist3 + (size_t)a*NBIN + (size_t)c*1024;
  u32* pref = pref3 + (size_t)a*(NBIN+1) + (size_t)c*1024;
  u32 loc[4]; u32 s = 0;
  #pragma unroll
  for(int j=0;j<4;++j){ loc[j] = h[t*4+j]; s += loc[j]; }
  part[t] = s; __syncthreads();
  for(int off=1;off<256;off<<=1){
    u32 u = (t >= off) ? part[t-off] : 0u;
    __syncthreads(); part[t] += u; __syncthreads();
  }
  u32 run = bbase[blk] + part[t] - s;
  #pragma unroll
  for(int j=0;j<4;++j){ pref[t*4+j] = run; run += loc[j]; }
}

// ----------------- scatter / rank+score -----------------
__global__ void k_scatter3(const u32* __restrict__ keys3, const u32* __restrict__ pref3,
                           u32* __restrict__ cnt3, u32* __restrict__ lo3){
  int i = blockIdx.x*256 + threadIdx.x;
  if(i >= NM) return;
  #pragma unroll
  for(int a=0;a<3;++a){
    u32 k = keys3[(size_t)a*NM + i];
    u32 b = k >> 16;
    u32 pos = pref3[(size_t)a*(NBIN+1) + b] + atomicAdd(&cnt3[(size_t)a*NBIN + b], 1u);
    lo3[(size_t)a*NM + pos] = k & 0xFFFFu;
  }
}

__global__ void k_rank3score(const u32* __restrict__ keys3, const u32* __restrict__ pref3,
                             const u32* __restrict__ lo3, u32* __restrict__ keysS, u32* __restrict__ histS){
  int i = blockIdx.x*256 + threadIdx.x;
  if(i >= NM) return;
  float rr[3];
  #pragma unroll
  for(int a=0;a<3;++a){
    u32 k = keys3[(size_t)a*NM + i];
    u32 b = k >> 16, my = k & 0xFFFFu;
    const u32* pref = pref3 + (size_t)a*(NBIN+1);
    const u32* lo = lo3 + (size_t)a*NM;
    u32 s = pref[b], e = pref[b+1];
    u32 nl = 0, ne = 0;
    for(u32 j=s;j<e;++j){ u32 u = lo[j]; nl += (u < my); ne += (u == my); }
    u32 left = s + nl, right = left + ne;
    rr[a] = (float)(left + right - 1) * (1.0f/131072.0f);
  }
  float sc = __fadd_rn(__fadd_rn(__fmul_rn(rr[0],rr[0]), __fmul_rn(rr[1],rr[1])), __fmul_rn(rr[2],rr[2]));
  u32 k = __float_as_uint(sc);
  keysS[i] = k;
  atomicAdd(&histS[k >> 16], 1u);
}

// ----------------- top-k -----------------
__global__ __launch_bounds__(1024) void k_sel1(const u32* __restrict__ hist, Ctrl* ctrl){
  __shared__ u32 part[1024];
  int t = threadIdx.x;
  u32 base = t*64, s = 0;
  for(int j=0;j<64;++j) s += hist[base+j];
  part[t] = s; __syncthreads();
  for(int off=1;off<1024;off<<=1){
    u32 v = (t+off < 1024) ? part[t+off] : 0u;
    __syncthreads(); part[t] += v; __syncthreads();
  }
  u32 above = part[t] - s;
  if(above < (u32)KS && above + s >= (u32)KS){
    u32 cum = above;
    for(int j=63;j>=0;--j){
      u32 c = hist[base+j];
      if(cum + c >= (u32)KS){ ctrl->T = (u32)(base+j) << 16; ctrl->candcnt = 0; break; }
      cum += c;
    }
  }
}

__global__ void k_collect(const u32* __restrict__ keys, Ctrl* ctrl, u64* __restrict__ cand){
  int i = blockIdx.x*256 + threadIdx.x;
  if(i >= NM) return;
  u32 k = keys[i];
  if(k >= ctrl->T){
    u32 p = atomicAdd(&ctrl->candcnt, 1u);
    if(p < (u32)CCAP) cand[p] = ((u64)(~k) << 32) | (u32)i;
  }
}

__global__ __launch_bounds__(1024) void k_sortsel(const u64* __restrict__ cand, const Ctrl* ctrl, int* __restrict__ idx){
  __shared__ u64 sm[CCAP];
  int t = threadIdx.x;
  u32 n = ctrl->candcnt; if(n > (u32)CCAP) n = CCAP;
  for(int i=t;i<CCAP;i+=1024) sm[i] = (i < (int)n) ? cand[i] : 0xFFFFFFFFFFFFFFFFull;
  __syncthreads();
  for(int k=2;k<=CCAP;k<<=1){
    for(int j=k>>1;j>0;j>>=1){
      for(int i=t;i<CCAP;i+=1024){
        int ixj = i ^ j;
        if(ixj > i){
          bool up = ((i & k) == 0);
          u64 a = sm[i], b = sm[ixj];
          if((a > b) == up){ sm[i] = b; sm[ixj] = a; }
        }
      }
      __syncthreads();
    }
  }
  if(t < KS) idx[t] = (int)(sm[t] & 0xFFFFFFFFu);
}

// ----------------- gather (hm/ht as bf16) -----------------
__global__ void k_gather(const int* __restrict__ idx,
                         const float* __restrict__ mv, const float* __restrict__ mnv,
                         const float* __restrict__ mrew,
                         const int* __restrict__ aim, const int* __restrict__ ait,
                         const float* __restrict__ amw1, const float* __restrict__ amb1,
                         const float* __restrict__ atw1, const float* __restrict__ atb1,
                         const float* __restrict__ start, const float* __restrict__ x,
                         const float* __restrict__ pos,
                         float* __restrict__ vecs, float* __restrict__ outnext,
                         u16* __restrict__ hm, u16* __restrict__ ht,
                         float* __restrict__ rew, float* __restrict__ outrew){
  int k = blockIdx.x;
  int t = threadIdx.x;
  if(k < KS){
    int row = idx[k];
    const float* a = mv  + (size_t)row*HD;
    const float* b = mnv + (size_t)row*HD;
    const float* pz = pos + (size_t)(2*k+1)*HD;
    float* vr = vecs + (size_t)(2*k+1)*HD;
    for(int c=t;c<HD;c+=256){
      vr[c] = a[c] + pz[c];
      outnext[(size_t)k*HD+c] = b[c];
    }
    int am = aim[row], at = ait[row];
    for(int j=t;j<HD;j+=256){
      hm[(size_t)k*HD+j] = f2bf(gelu_f(amw1[(size_t)j*9 + am] + amb1[j]));
      ht[(size_t)k*HD+j] = f2bf(gelu_f(atw1[(size_t)j*4 + at] + atb1[j]));
    }
    if(t == 0){ float r = mrew[row]; rew[k] = r; outrew[k] = r; }
  } else {
    for(int c=t;c<HD;c+=256){
      vecs[c] = start[c] + pos[c];
      vecs[(size_t)(SQ-1)*HD + c] = x[c] + pos[(size_t)(SQ-1)*HD + c];
    }
  }
}

// ----------------- bf16 MFMA split-K GEMM (global_load_lds, dbuf, 1 barrier/step) -----------------
// A: [M][lda] bf16, B: [N][K] bf16. 64x64 tile, 4 waves (2x2 of 32x32), BK=32. P[z] partials fp32.
__device__ __forceinline__ void gemm_body(u16* As, u16* Bs, const u16* __restrict__ A, const u16* __restrict__ B,
        float* __restrict__ P, int M, int N, int K, int S, int nbm, int lda, int tile){
  int bm = (tile % nbm) * 64;
  int tmp = tile / nbm;
  int z  = tmp % S;
  int bn = (tmp / S) * 64;
  int Ks = K / S, kbeg = z*Ks;
  int nk = Ks >> 5;

  int t = threadIdx.x, lane = t & 63, w = t >> 6;
  // staging: wave w stages tile rows [w*16, w*16+16) for A and B
  int srow = w*16 + (lane >> 2);
  int clog = (lane & 3) ^ ((srow >> 1) & 3);   // pre-swizzled global k-chunk
  const u16* ga = A + (size_t)(bm + srow)*lda + kbeg + clog*8;
  const u16* gb = B + (size_t)(bn + srow)*K  + kbeg + clog*8;
  u16* la = As + w*512;   // lane i -> bytes [i*16), covering (row=w*16+i/4, cphys=i%3...i&3)
  u16* lb = Bs + w*512;

  int wm = (w >> 1)*32, wn = (w & 1)*32;
  int lr = lane & 15, lg = lane >> 4;
  int r0 = wm + lr, r1 = r0 + 16;
  int c0 = wn + lr, c1 = c0 + 16;
  int aoff0 = r0*32 + ((lg ^ ((r0>>1)&3))*8);
  int aoff1 = r1*32 + ((lg ^ ((r1>>1)&3))*8);
  int boff0 = c0*32 + ((lg ^ ((c0>>1)&3))*8);
  int boff1 = c1*32 + ((lg ^ ((c1>>1)&3))*8);

  f32x4v acc00 = {0,0,0,0}, acc01 = {0,0,0,0}, acc10 = {0,0,0,0}, acc11 = {0,0,0,0};

  gload16(ga, la);
  gload16(gb, lb);
  ga += 32; gb += 32;
  __syncthreads();

  for(int kk = 0; kk < nk; ++kk){
    int cur = (kk & 1) * 2048;
    if(kk + 1 < nk){
      int nxt = 2048 - cur;
      gload16(ga, la + nxt);
      gload16(gb, lb + nxt);
      ga += 32; gb += 32;
    }
    bf16x8 a0 = *(const bf16x8*)&As[cur + aoff0];
    bf16x8 a1 = *(const bf16x8*)&As[cur + aoff1];
    bf16x8 b0 = *(const bf16x8*)&Bs[cur + boff0];
    bf16x8 b1 = *(const bf16x8*)&Bs[cur + boff1];
    acc00 = __builtin_amdgcn_mfma_f32_16x16x32_bf16(a0, b0, acc00, 0, 0, 0);
    acc01 = __builtin_amdgcn_mfma_f32_16x16x32_bf16(a0, b1, acc01, 0, 0, 0);
    acc10 = __builtin_amdgcn_mfma_f32_16x16x32_bf16(a1, b0, acc10, 0, 0, 0);
    acc11 = __builtin_amdgcn_mfma_f32_16x16x32_bf16(a1, b1, acc11, 0, 0, 0);
    __syncthreads();
  }

  size_t zbase = (size_t)z * (size_t)M;
  #pragma unroll
  for(int r=0;r<4;++r){
    int row0 = bm + wm + lg*4 + r;
    int row1 = row0 + 16;
    int cc0 = bn + wn + lr, cc1 = cc0 + 16;
    if(row0 < M){
      P[(zbase+row0)*N + cc0] = acc00[r];
      P[(zbase+row0)*N + cc1] = acc01[r];
    }
    if(row1 < M){
      P[(zbase+row1)*N + cc0] = acc10[r];
      P[(zbase+row1)*N + cc1] = acc11[r];
    }
  }
}

__global__ __launch_bounds__(256) void k_gemm(const u16* __restrict__ A, const u16* __restrict__ B,
        float* __restrict__ P, int M, int N, int K, int S, int nbm, int lda){
  __shared__ u16 As[4096];
  __shared__ u16 Bs[4096];
  u32 nwg = gridDim.x, orig = blockIdx.x;
  u32 swz = (orig & 7)*(nwg >> 3) + (orig >> 3);
  gemm_body(As, Bs, A, B, P, M, N, K, S, nbm, lda, (int)swz);
}

__global__ __launch_bounds__(256) void k_actgemm(const u16* __restrict__ hm, const u16* __restrict__ ht,
        const u16* __restrict__ amw2, const u16* __restrict__ atw2,
        float* __restrict__ part, float* __restrict__ part2){
  __shared__ u16 As[4096];
  __shared__ u16 Bs[4096];
  int which = blockIdx.x >> 8, tile = blockIdx.x & 255;
  gemm_body(As, Bs, which ? ht : hm, which ? atw2 : amw2, which ? part2 : part,
            KS, HD, HD, 8, 2, HD, tile);
}

// ----------------- flat epilogue: sum S_ slices + bias (+gelu), fp32 or bf16 out -----------------
template<int S_, int ACT, bool BF>
__global__ __launch_bounds__(256) void k_finS(const float* __restrict__ P, const float* __restrict__ bias,
                                              float* __restrict__ C, u16* __restrict__ Cb, int MN4, int Nd){
  int i4 = blockIdx.x*256 + threadIdx.x;
  if(i4 >= MN4) return;
  size_t off = (size_t)i4*4;
  size_t MN = (size_t)MN4*4;
  float4 v = *(const float4*)&P[off];
  #pragma unroll
  for(int z=1;z<S_;++z){
    float4 q = *(const float4*)&P[(size_t)z*MN + off];
    v.x += q.x; v.y += q.y; v.z += q.z; v.w += q.w;
  }
  int j = (i4 % (Nd/4))*4;
  float4 b4 = *(const float4*)&bias[j];
  v.x += b4.x; v.y += b4.y; v.z += b4.z; v.w += b4.w;
  if(ACT == 1){ v.x = gelu_f(v.x); v.y = gelu_f(v.y); v.z = gelu_f(v.z); v.w = gelu_f(v.w); }
  if(BF){
    u16 r[4] = { f2bf(v.x), f2bf(v.y), f2bf(v.z), f2bf(v.w) };
    u64 pk; __builtin_memcpy(&pk, r, 8);
    *(u64*)&Cb[off] = pk;
  } else {
    *(float4*)&C[off] = v;
  }
}

// ----------------- row finish: sum S_ + bias + residual; LN->lnb(bf16) | copy-out+vhin(bf16) -----------------
template<int S_, bool LN>
__global__ __launch_bounds__(256) void k_finrow(const float* __restrict__ P, const float* __restrict__ bias,
                                                float* __restrict__ vecs, const float* __restrict__ lw,
                                                const float* __restrict__ lb, u16* __restrict__ lnb,
                                                float* __restrict__ outp, u16* __restrict__ vhin){
  __shared__ float red[256];
  int row = blockIdx.x, t = threadIdx.x;
  int j = t*4;
  float4 v = *(const float4*)&P[(size_t)row*HD + j];
  #pragma unroll
  for(int z=1;z<S_;++z){
    float4 p = *(const float4*)&P[((size_t)z*SQ + row)*HD + j];
    v.x += p.x; v.y += p.y; v.z += p.z; v.w += p.w;
  }
  float4 b4 = *(const float4*)&bias[j];
  float4 r4 = *(const float4*)&vecs[(size_t)row*HD + j];
  v.x += b4.x + r4.x; v.y += b4.y + r4.y; v.z += b4.z + r4.z; v.w += b4.w + r4.w;
  *(float4*)&vecs[(size_t)row*HD + j] = v;
  if(LN){
    red[t] = v.x+v.y+v.z+v.w; __syncthreads();
    for(int o=128;o>0;o>>=1){ if(t<o) red[t]+=red[t+o]; __syncthreads(); }
    float m = red[0]*(1.0f/HD); __syncthreads();
    float dx=v.x-m, dy=v.y-m, dz=v.z-m, dw=v.w-m;
    red[t] = dx*dx+dy*dy+dz*dz+dw*dw; __syncthreads();
    for(int o=128;o>0;o>>=1){ if(t<o) red[t]+=red[t+o]; __syncthreads(); }
    float den = sqrtf(red[0]*(1.0f/HD) + 1e-5f);
    float4 w4 = *(const float4*)&lw[j];
    float4 lb4 = *(const float4*)&lb[j];
    u16 r[4] = { f2bf(dx/den*w4.x + lb4.x), f2bf(dy/den*w4.y + lb4.y),
                 f2bf(dz/den*w4.z + lb4.z), f2bf(dw/den*w4.w + lb4.w) };
    u64 pk; __builtin_memcpy(&pk, r, 8);
    *(u64*)&lnb[(size_t)row*HD + j] = pk;
  } else {
    if(row >= 1) *(float4*)&outp[(size_t)(row-1)*HD + j] = v;
    if(row & 1){
      int vr = (row-1) >> 1;
      u16 r[4] = { f2bf(v.x), f2bf(v.y), f2bf(v.z), f2bf(v.w) };
      u64 pk; __builtin_memcpy(&pk, r, 8);
      *(u64*)&vhin[(size_t)vr*HD + j] = pk;
    }
  }
}

// ----------------- finav + LN1 (lnb bf16) -----------------
__global__ __launch_bounds__(256) void k_finavln(const float* __restrict__ Pm, const float* __restrict__ Pt,
                                                 const float* __restrict__ bm_, const float* __restrict__ bt_,
                                                 const float* __restrict__ pos, float* __restrict__ vecs,
                                                 const float* __restrict__ lw, const float* __restrict__ lb,
                                                 u16* __restrict__ lnb){
  __shared__ float red[256];
  int row = blockIdx.x, t = threadIdx.x;
  int j = t*4;
  float4 v;
  if(row >= 2 && row <= 256 && ((row & 1) == 0)){
    int k = (row-2) >> 1;
    float4 s = {0,0,0,0};
    #pragma unroll
    for(int z=0;z<8;++z){
      float4 a = *(const float4*)&Pm[((size_t)z*KS + k)*HD + j];
      float4 b = *(const float4*)&Pt[((size_t)z*KS + k)*HD + j];
      s.x += a.x+b.x; s.y += a.y+b.y; s.z += a.z+b.z; s.w += a.w+b.w;
    }
    float4 bm4 = *(const float4*)&bm_[j];
    float4 bt4 = *(const float4*)&bt_[j];
    float4 p4 = *(const float4*)&pos[(size_t)row*HD + j];
    v.x = 0.5f*(s.x + bm4.x + bt4.x) + p4.x;
    v.y = 0.5f*(s.y + bm4.y + bt4.y) + p4.y;
    v.z = 0.5f*(s.z + bm4.z + bt4.z) + p4.z;
    v.w = 0.5f*(s.w + bm4.w + bt4.w) + p4.w;
    *(float4*)&vecs[(size_t)row*HD + j] = v;
  } else {
    v = *(const float4*)&vecs[(size_t)row*HD + j];
  }
  red[t] = v.x+v.y+v.z+v.w; __syncthreads();
  for(int o=128;o>0;o>>=1){ if(t<o) red[t]+=red[t+o]; __syncthreads(); }
  float m = red[0]*(1.0f/HD); __syncthreads();
  float dx=v.x-m, dy=v.y-m, dz=v.z-m, dw=v.w-m;
  red[t] = dx*dx+dy*dy+dz*dz+dw*dw; __syncthreads();
  for(int o=128;o>0;o>>=1){ if(t<o) red[t]+=red[t+o]; __syncthreads(); }
  float den = sqrtf(red[0]*(1.0f/HD) + 1e-5f);
  float4 w4 = *(const float4*)&lw[j];
  float4 lb4 = *(const float4*)&lb[j];
  u16 r[4] = { f2bf(dx/den*w4.x + lb4.x), f2bf(dy/den*w4.y + lb4.y),
               f2bf(dz/den*w4.z + lb4.z), f2bf(dw/den*w4.w + lb4.w) };
  u64 pk; __builtin_memcpy(&pk, r, 8);
  *(u64*)&lnb[(size_t)row*HD + j] = pk;
}

// ----------------- attention (bf16 out) -----------------
__global__ void k_attn(const float* __restrict__ qkv, u16* __restrict__ outp){
  __shared__ float qv[64];
  __shared__ float p[SQ];
  __shared__ float red[256];
  int q = blockIdx.x, h = blockIdx.y, t = threadIdx.x;
  if(t < 64) qv[t] = qkv[(size_t)q*3072 + h*64 + t];
  __syncthreads();
  int nk = q + 1;
  float lmax = -1e30f;
  for(int j=t;j<nk;j+=256){
    const float* kr = qkv + (size_t)j*3072 + 1024 + h*64;
    float d = 0.f;
    for(int c=0;c<64;++c) d += qv[c]*kr[c];
    d *= 0.125f;
    p[j] = d;
    lmax = fmaxf(lmax, d);
  }
  red[t] = lmax; __syncthreads();
  for(int o=128;o>0;o>>=1){ if(t<o) red[t] = fmaxf(red[t], red[t+o]); __syncthreads(); }
  float m = red[0];
  __syncthreads();
  float lsum = 0.f;
  for(int j=t;j<nk;j+=256){ float e = expf(p[j]-m); p[j] = e; lsum += e; }
  red[t] = lsum; __syncthreads();
  for(int o=128;o>0;o>>=1){ if(t<o) red[t] += red[t+o]; __syncthreads(); }
  float inv = 1.0f/red[0];
  __syncthreads();
  int d = t & 63, g = t >> 6;
  float acc = 0.f;
  for(int j=g;j<nk;j+=4) acc += p[j]*qkv[(size_t)j*3072 + 2048 + h*64 + d];
  red[t] = acc; __syncthreads();
  if(g == 0){
    float o4 = red[d] + red[64+d] + red[128+d] + red[192+d];
    outp[(size_t)q*HD + h*64 + d] = f2bf(o4*inv);
  }
}

// ----------------- value head finish -----------------
__global__ __launch_bounds__(256) void k_vpfin(const float* __restrict__ P, const float* __restrict__ vb1,
                                               const float* __restrict__ vw2, float* __restrict__ vp){
  __shared__ float red[256];
  int r = blockIdx.x, t = threadIdx.x;
  float s = 0.f;
  for(int c=t;c<4096;c+=256){
    float v = P[(size_t)r*4096 + c];
    #pragma unroll
    for(int z=1;z<4;++z) v += P[((size_t)z*129 + r)*4096 + c];
    s += gelu_f(v + vb1[c]) * vw2[c];
  }
  red[t]=s; __syncthreads();
  for(int o=128;o>0;o>>=1){ if(t<o) red[t]+=red[t+o]; __syncthreads(); }
  if(t == 0) vp[r] = red[0];
}

__global__ void k_outsmall(const float* __restrict__ vp, const float* __restrict__ b2,
                           const float* __restrict__ rew, float* __restrict__ outp){
  int t = threadIdx.x;
  float bb = b2[0];
  if(t == 0) outp[OUT_VP] = vp[KS] + bb;
  if(t < KS){
    float d = (vp[t] + bb) - rew[t];
    outp[OUT_LOSS + t] = d*d;
    outp[OUT_REWO + t] = rew[t];
  }
}

extern "C" void kernel_launch(void* const* d_in, const int* in_sizes, int n_in,
                              void* d_out, int out_size, void* d_ws, size_t ws_size,
                              hipStream_t stream){
  const float* x     = (const float*)d_in[0];
  const float* mv    = (const float*)d_in[1];
  const float* mnv   = (const float*)d_in[2];
  const float* surp  = (const float*)d_in[3];
  const float* mrew  = (const float*)d_in[4];
  const float* noise = (const float*)d_in[5];
  const int*   aim   = (const int*)d_in[6];
  const int*   ait   = (const int*)d_in[7];
  const float* start = (const float*)d_in[8];
  const float* pos   = (const float*)d_in[9];
  const float* inW = (const float*)d_in[10]; const float* inB = (const float*)d_in[11];
  const float* oW  = (const float*)d_in[12]; const float* oB  = (const float*)d_in[13];
  const float* l1w = (const float*)d_in[14]; const float* l1b = (const float*)d_in[15];
  const float* l2w = (const float*)d_in[16]; const float* l2b = (const float*)d_in[17];
  const float* f1w = (const float*)d_in[18]; const float* f1b = (const float*)d_in[19];
  const float* f2w = (const float*)d_in[20]; const float* f2b = (const float*)d_in[21];
  const float* amw1= (const float*)d_in[22]; const float* amb1= (const float*)d_in[23];
  const float* amw2= (const float*)d_in[24]; const float* amb2= (const float*)d_in[25];
  const float* atw1= (const float*)d_in[26]; const float* atb1= (const float*)d_in[27];
  const float* atw2= (const float*)d_in[28]; const float* atb2= (const float*)d_in[29];
  const float* vw1 = (const float*)d_in[30]; const float* vb1 = (const float*)d_in[31];
  const float* vw2 = (const float*)d_in[32]; const float* vb2 = (const float*)d_in[33];

  float* out = (float*)d_out;
  char* ws = (char*)d_ws;
  u32*  hist3 = (u32*)(ws+OFF_H3);
  u32*  cnt3  = (u32*)(ws+OFF_C3);
  u32*  histS = (u32*)(ws+OFF_HS);
  u32*  bsum  = (u32*)(ws+OFF_BS);
  u32*  bbase = (u32*)(ws+OFF_BB);
  float* vp   = (float*)(ws+OFF_VPB);
  float* xn   = (float*)(ws+OFF_XN);
  u32*  pref3 = (u32*)(ws+OFF_P3);
  u32*  keys3 = (u32*)(ws+OFF_K3);
  u32*  lo3   = (u32*)(ws+OFF_L3);
  u32*  keysS = (u32*)(ws+OFF_KSC);
  u64*  cand  = (u64*)(ws+OFF_CAND);
  Ctrl* ctrl  = (Ctrl*)(ws+OFF_CTRL);
  int*  idxb  = (int*)(ws+OFF_IDX);
  float* rew  = (float*)(ws+OFF_REW);
  u16*  hm    = (u16*)(ws+OFF_HM);
  u16*  ht    = (u16*)(ws+OFF_HT);
  float* vecs = (float*)(ws+OFF_VECS);
  u16*  lnb   = (u16*)(ws+OFF_LNB);
  float* qkvb = (float*)(ws+OFF_QKV);
  u16*  attn  = (u16*)(ws+OFF_ATT);
  u16*  ffh   = (u16*)(ws+OFF_FFH);
  u16*  vhin  = (u16*)(ws+OFF_VHIN);
  u16*  wb    = (u16*)(ws+OFF_WB);
  float* part = (float*)(ws+OFF_PART);
  float* part2= part + (size_t)8*KS*HD;

  u16* inW_bf = wb + WB_IN;
  u16* oW_bf  = wb + WB_O;
  u16* f1w_bf = wb + WB_F1;
  u16* f2w_bf = wb + WB_F2;
  u16* am_bf  = wb + WB_AM;
  u16* at_bf  = wb + WB_AT;
  u16* vh_bf  = wb + WB_VH;

  dim3 b256(256);
  int gN = NM/256;

  (void)hipMemsetAsync(ws, 0, ZERO_BYTES, stream);

  // ---- weight conversion (independent of everything) ----
  {
    WCA a;
    const float* srcs[7] = { inW, oW, f1w, f2w, amw2, atw2, vw1 };
    u16* dsts[7] = { inW_bf, oW_bf, f1w_bf, f2w_bf, am_bf, at_bf, vh_bf };
    u32 sizes4[7] = { 4*3*HD*HD/4, 4*HD*HD/4, 4*4*HD*HD/4, 4*4*HD*HD/4, HD*HD/4, HD*HD/4, 4*HD*HD/4 };
    u32 cum = 0;
    for(int j=0;j<7;++j){
      a.seg[j].s = srcs[j]; a.seg[j].d = dsts[j];
      a.seg[j].base4 = cum; cum += sizes4[j]; a.seg[j].end4 = cum;
    }
    a.tot4 = cum;
    hipLaunchKernelGGL(k_wconv, dim3((cum + 255)/256), b256, 0, stream, a);
  }

  // ---- scoring / ranking / top-k ----
  hipLaunchKernelGGL(k_xn, dim3(1), b256, 0, stream, x, xn);
  hipLaunchKernelGGL(k_simkey, dim3(NM/4), b256, 0, stream, mv, xn, surp, noise, keys3, hist3);
  hipLaunchKernelGGL(k_scanA, dim3(192), b256, 0, stream, hist3, bsum);
  hipLaunchKernelGGL(k_scanB, dim3(1), b256, 0, stream, bsum, bbase, pref3);
  hipLaunchKernelGGL(k_scanC, dim3(192), b256, 0, stream, hist3, bbase, pref3);
  hipLaunchKernelGGL(k_scatter3, dim3(gN), b256, 0, stream, keys3, pref3, cnt3, lo3);
  hipLaunchKernelGGL(k_rank3score, dim3(gN), b256, 0, stream, keys3, pref3, lo3, keysS, histS);
  hipLaunchKernelGGL(k_sel1, dim3(1), dim3(1024), 0, stream, histS, ctrl);
  hipLaunchKernelGGL(k_collect, dim3(gN), b256, 0, stream, keysS, ctrl, cand);
  hipLaunchKernelGGL(k_sortsel, dim3(1), dim3(1024), 0, stream, cand, ctrl, idxb);

  // ---- gather + action MLPs + assembly/LN1 ----
  hipLaunchKernelGGL(k_gather, dim3(KS+1), b256, 0, stream, idxb, mv, mnv, mrew, aim, ait,
                     amw1, amb1, atw1, atb1, start, x, pos,
                     vecs, out + OUT_NEXT, hm, ht, rew, out + OUT_REWO);
  hipLaunchKernelGGL(k_actgemm, dim3(512), b256, 0, stream, hm, ht, am_bf, at_bf, part, part2);
  hipLaunchKernelGGL(k_finavln, dim3(SQ), b256, 0, stream, part, part2, amb2, atb2, pos, vecs, l1w, l1b, lnb);

  // ---- transformer ----
  for(int l=0;l<NL;++l){
    hipLaunchKernelGGL(k_gemm, dim3(480), b256, 0, stream, lnb, inW_bf + (size_t)l*3*HD*HD, part, SQ, 3*HD, HD, 2, 5, HD);
    hipLaunchKernelGGL((k_finS<2,0,false>), dim3(774), b256, 0, stream, part, inB + (size_t)l*3*HD, qkvb, (u16*)nullptr, SQ*3*HD/4, 3*HD);
    hipLaunchKernelGGL(k_attn, dim3(SQ, 16), b256, 0, stream, qkvb, attn);
    hipLaunchKernelGGL(k_gemm, dim3(640), b256, 0, stream, attn, oW_bf + (size_t)l*HD*HD, part, SQ, HD, HD, 8, 5, HD);
    hipLaunchKernelGGL((k_finrow<8,true>), dim3(SQ), b256, 0, stream, part, oB + (size_t)l*HD, vecs,
                       l2w + (size_t)l*HD, l2b + (size_t)l*HD, lnb, (float*)nullptr, (u16*)nullptr);
    hipLaunchKernelGGL(k_gemm, dim3(640), b256, 0, stream, lnb, f1w_bf + (size_t)l*4*HD*HD, part, SQ, 4*HD, HD, 2, 5, HD);
    hipLaunchKernelGGL((k_finS<2,1,true>), dim3(1032), b256, 0, stream, part, f1b + (size_t)l*4*HD, (float*)nullptr, ffh, SQ*4*HD/4, 4*HD);
    hipLaunchKernelGGL(k_gemm, dim3(640), b256, 0, stream, ffh, f2w_bf + (size_t)l*HD*4*HD, part, SQ, HD, 4*HD, 8, 5, 4*HD);
    if(l < NL-1)
      hipLaunchKernelGGL((k_finrow<8,true>), dim3(SQ), b256, 0, stream, part, f2b + (size_t)l*HD, vecs,
                         l1w + (size_t)(l+1)*HD, l1b + (size_t)(l+1)*HD, lnb, (float*)nullptr, (u16*)nullptr);
    else
      hipLaunchKernelGGL((k_finrow<8,false>), dim3(SQ), b256, 0, stream, part, f2b + (size_t)l*HD, vecs,
                         (const float*)nullptr, (const float*)nullptr, (u16*)nullptr, out, vhin);
  }

  // ---- value head ----
  hipLaunchKernelGGL(k_gemm, dim3(768), b256, 0, stream, vhin, vh_bf, part, KS+1, 4*HD, HD, 4, 3, HD);
  hipLaunchKernelGGL(k_vpfin, dim3(KS+1), b256, 0, stream, part, vb1, vw2, vp);
  hipLaunchKernelGGL(k_outsmall, dim3(1), b256, 0, stream, vp, vb2, rew, out);
}

// Round 9
// 883.020 us; speedup vs baseline: 3.2097x; 1.0730x over previous
//
#include <hip/hip_runtime.h>
#include <hip/hip_bf16.h>
#include <math.h>
#include <stdint.h>

typedef unsigned int u32;
typedef unsigned short u16;
typedef unsigned long long u64;

#define NM   65536
#define HD   1024
#define KS   128
#define SQ   258
#define NL   4
#define NBIN 65536
#define CCAP 2048

using bf16x8 = __attribute__((ext_vector_type(8))) short;
using f32x4v = __attribute__((ext_vector_type(4))) float;

static constexpr size_t A256(size_t x){ return (x + 255) & ~(size_t)255; }

// ---- zeroed region (folded into k_wconv): hist3 + cnt3 + histS = 1792 KB ----
constexpr size_t OFF_H3   = 0;                                  // 3*NBIN u32 = 768KB
constexpr size_t OFF_C3   = OFF_H3 + (size_t)3*NBIN*4;          // 768KB
constexpr size_t OFF_HS   = OFF_C3 + (size_t)3*NBIN*4;          // 256KB
constexpr size_t ZERO_BYTES = OFF_HS + (size_t)NBIN*4;          // 1835008 = 1792*1024
constexpr u32 ZBLK = 1792;
// ---- rest ----
constexpr size_t OFF_BS   = A256(ZERO_BYTES);                       // 192 u32
constexpr size_t OFF_P3   = A256(OFF_BS + 192*4);                   // 3*(NBIN+1) u32
constexpr size_t OFF_K3   = A256(OFF_P3 + (size_t)3*(NBIN+1)*4);    // 3*NM u32
constexpr size_t OFF_L3   = A256(OFF_K3 + (size_t)3*NM*4);
constexpr size_t OFF_KSC  = A256(OFF_L3 + (size_t)3*NM*4);
constexpr size_t OFF_IDX  = A256(OFF_KSC + (size_t)NM*4);
constexpr size_t OFF_REW  = A256(OFF_IDX  + (size_t)KS*4);
constexpr size_t OFF_HM   = A256(OFF_REW  + (size_t)KS*4);            // u16
constexpr size_t OFF_HT   = A256(OFF_HM   + (size_t)KS*HD*2);
constexpr size_t OFF_VECS = A256(OFF_HT   + (size_t)KS*HD*2);         // f32
constexpr size_t OFF_LNB  = A256(OFF_VECS + (size_t)SQ*HD*4);         // u16
constexpr size_t OFF_QKV  = A256(OFF_LNB  + (size_t)SQ*HD*2);         // u16 [258][3072]
constexpr size_t OFF_ATT  = A256(OFF_QKV  + (size_t)SQ*3*HD*2);       // u16
constexpr size_t OFF_FFH  = A256(OFF_ATT  + (size_t)SQ*HD*2);         // u16 [258][4096]
constexpr size_t OFF_VHIN = A256(OFF_FFH  + (size_t)SQ*4*HD*2);       // u16 [129][1024]
constexpr size_t OFF_WB   = A256(OFF_VHIN + (size_t)129*HD*2);        // u16 weights
constexpr size_t NWELEM   = 56623104;
constexpr size_t OFF_PART = A256(OFF_WB + NWELEM*2);                  // u16 partials (8MB+)

constexpr size_t WB_IN = 0;
constexpr size_t WB_O  = WB_IN + (size_t)4*3*HD*HD;
constexpr size_t WB_F1 = WB_O  + (size_t)4*HD*HD;
constexpr size_t WB_F2 = WB_F1 + (size_t)4*4*HD*HD;
constexpr size_t WB_AM = WB_F2 + (size_t)4*4*HD*HD;
constexpr size_t WB_AT = WB_AM + (size_t)HD*HD;
constexpr size_t WB_VH = WB_AT + (size_t)HD*HD;

// output layout (floats)
constexpr int OUT_NEXT = 257*HD;
constexpr int OUT_VP   = OUT_NEXT + KS*HD;
constexpr int OUT_LOSS = OUT_VP + 1;
constexpr int OUT_REWO = OUT_LOSS + KS;

struct Ctrl { u32 b1, above1, T, candcnt; };

__device__ __forceinline__ float gelu_f(float v){
  return 0.5f*v*(1.0f + erff(v*0.70710678118654752440f));
}

__device__ __forceinline__ u16 f2bf(float f){
  __hip_bfloat16 h = __float2bfloat16(f);
  u16 s; __builtin_memcpy(&s, &h, sizeof(u16));
  return s;
}

__device__ __forceinline__ float bf2f(u16 v){ return __uint_as_float(((u32)v) << 16); }

__device__ __forceinline__ float4 unpk4(u64 pk){
  u32 lo = (u32)pk, hi = (u32)(pk >> 32);
  float4 v;
  v.x = __uint_as_float(lo << 16);
  v.y = __uint_as_float(lo & 0xFFFF0000u);
  v.z = __uint_as_float(hi << 16);
  v.w = __uint_as_float(hi & 0xFFFF0000u);
  return v;
}

__device__ __forceinline__ u64 pk4(float4 v){
  u16 r[4] = { f2bf(v.x), f2bf(v.y), f2bf(v.z), f2bf(v.w) };
  u64 pk; __builtin_memcpy(&pk, r, 8);
  return pk;
}

__device__ __forceinline__ u32 fkey(float v){
  u32 b = __float_as_uint(v);
  return (b >> 31) ? ~b : (b | 0x80000000u);
}

__device__ __forceinline__ void gload16(const u16* g, u16* l){
  __builtin_amdgcn_global_load_lds(
      (const __attribute__((address_space(1))) unsigned int*)g,
      (__attribute__((address_space(3))) unsigned int*)l, 16, 0, 0);
}

// ----------------- weight conversion fp32 -> bf16 (+ zero hist regions) -----------------
struct WSeg { const float* s; u16* d; u32 base4, end4; };
struct WCA { WSeg seg[7]; u32 tot4; u32* z; };
__global__ __launch_bounds__(256) void k_wconv(WCA a){
  if(blockIdx.x < ZBLK) a.z[blockIdx.x*256 + threadIdx.x] = 0u;
  u32 i = blockIdx.x*256 + threadIdx.x;
  if(i >= a.tot4) return;
  #pragma unroll
  for(int j=0;j<7;++j){
    if(i < a.seg[j].end4){
      u32 off = i - a.seg[j].base4;
      float4 v = *(const float4*)&a.seg[j].s[(size_t)off*4];
      *(u64*)&a.seg[j].d[(size_t)off*4] = pk4(v);
      return;
    }
  }
}

// ----------------- fused xnorm + sim + keys + hist (8 rows/block) -----------------
__global__ __launch_bounds__(256) void k_simkey(const float* __restrict__ mv, const float* __restrict__ x,
                                                const float* __restrict__ surp, const float* __restrict__ noise,
                                                u32* __restrict__ keys3, u32* __restrict__ hist3){
  __shared__ float xs[HD];
  __shared__ float red[256];
  int t = threadIdx.x;
  float s = 0.f;
  for(int i=t;i<HD;i+=256){ float v=x[i]; s += v*v; }
  red[t]=s; __syncthreads();
  for(int o=128;o>0;o>>=1){ if(t<o) red[t]+=red[t+o]; __syncthreads(); }
  float nrm = fmaxf(sqrtf(red[0]), 1e-8f);
  for(int i=t;i<HD;i+=256) xs[i] = x[i]/nrm;
  __syncthreads();
  int lane = t & 63, w = t >> 6;
  #pragma unroll
  for(int rep=0;rep<2;++rep){
    int row = blockIdx.x*8 + rep*4 + w;
    const float4* p = (const float4*)(mv + (size_t)row*HD);
    const float4* q = (const float4*)xs;
    float d=0.f, ss=0.f;
    #pragma unroll
    for(int r=0;r<4;++r){
      float4 v = p[lane + 64*r]; float4 u = q[lane + 64*r];
      d  += v.x*u.x + v.y*u.y + v.z*u.z + v.w*u.w;
      ss += v.x*v.x + v.y*v.y + v.z*v.z + v.w*v.w;
    }
    for(int off=32;off>0;off>>=1){ d += __shfl_xor(d,off,64); ss += __shfl_xor(ss,off,64); }
    if(lane==0){
      float sim = d / fmaxf(sqrtf(ss),1e-8f);
      float vals[3] = { surp[row], sim, noise[row] };
      #pragma unroll
      for(int a=0;a<3;++a){
        u32 k = fkey(vals[a]);
        keys3[(size_t)a*NM + row] = k;
        atomicAdd(&hist3[(size_t)a*NBIN + (k >> 16)], 1u);
      }
    }
  }
}

// ----------------- scan: A (block sums) + C (inline base, per-chunk prefix) -----------------
__global__ __launch_bounds__(256) void k_scanA(const u32* __restrict__ hist3, u32* __restrict__ bsum){
  __shared__ u32 red[256];
  int blk = blockIdx.x;
  int t = threadIdx.x;
  const u32* h = hist3 + (size_t)(blk>>6)*NBIN + (size_t)(blk&63)*1024;
  u32 s = 0;
  #pragma unroll
  for(int j=0;j<4;++j) s += h[t*4+j];
  red[t]=s; __syncthreads();
  for(int o=128;o>0;o>>=1){ if(t<o) red[t]+=red[t+o]; __syncthreads(); }
  if(t==0) bsum[blk] = red[0];
}

__global__ __launch_bounds__(256) void k_scanC(const u32* __restrict__ hist3, const u32* __restrict__ bsum,
                                               u32* __restrict__ pref3){
  __shared__ u32 part[256];
  int blk = blockIdx.x;
  int t = threadIdx.x;
  int a = blk >> 6, c = blk & 63;
  u32 base = 0;
  for(int j=0;j<c;++j) base += bsum[a*64 + j];
  const u32* h = hist3 + (size_t)a*NBIN + (size_t)c*1024;
  u32* pref = pref3 + (size_t)a*(NBIN+1) + (size_t)c*1024;
  u32 loc[4]; u32 s = 0;
  #pragma unroll
  for(int j=0;j<4;++j){ loc[j] = h[t*4+j]; s += loc[j]; }
  part[t] = s; __syncthreads();
  for(int off=1;off<256;off<<=1){
    u32 u = (t >= off) ? part[t-off] : 0u;
    __syncthreads(); part[t] += u; __syncthreads();
  }
  u32 run = base + part[t] - s;
  #pragma unroll
  for(int j=0;j<4;++j){ pref[t*4+j] = run; run += loc[j]; }
  if(c == 63 && t == 255) pref3[(size_t)a*(NBIN+1) + NBIN] = NM;
}

// ----------------- scatter / rank+score -----------------
__global__ void k_scatter3(const u32* __restrict__ keys3, const u32* __restrict__ pref3,
                           u32* __restrict__ cnt3, u32* __restrict__ lo3){
  int i = blockIdx.x*256 + threadIdx.x;
  if(i >= NM) return;
  #pragma unroll
  for(int a=0;a<3;++a){
    u32 k = keys3[(size_t)a*NM + i];
    u32 b = k >> 16;
    u32 pos = pref3[(size_t)a*(NBIN+1) + b] + atomicAdd(&cnt3[(size_t)a*NBIN + b], 1u);
    lo3[(size_t)a*NM + pos] = k & 0xFFFFu;
  }
}

__global__ void k_rank3score(const u32* __restrict__ keys3, const u32* __restrict__ pref3,
                             const u32* __restrict__ lo3, u32* __restrict__ keysS, u32* __restrict__ histS){
  int i = blockIdx.x*256 + threadIdx.x;
  if(i >= NM) return;
  float rr[3];
  #pragma unroll
  for(int a=0;a<3;++a){
    u32 k = keys3[(size_t)a*NM + i];
    u32 b = k >> 16, my = k & 0xFFFFu;
    const u32* pref = pref3 + (size_t)a*(NBIN+1);
    const u32* lo = lo3 + (size_t)a*NM;
    u32 s = pref[b], e = pref[b+1];
    u32 nl = 0, ne = 0;
    for(u32 j=s;j<e;++j){ u32 u = lo[j]; nl += (u < my); ne += (u == my); }
    u32 left = s + nl, right = left + ne;
    rr[a] = (float)(left + right - 1) * (1.0f/131072.0f);
  }
  float sc = __fadd_rn(__fadd_rn(__fmul_rn(rr[0],rr[0]), __fmul_rn(rr[1],rr[1])), __fmul_rn(rr[2],rr[2]));
  u32 k = __float_as_uint(sc);
  keysS[i] = k;
  atomicAdd(&histS[k >> 16], 1u);
}

// ----------------- fused threshold + collect + bitonic sort -----------------
__global__ __launch_bounds__(1024) void k_selsort(const u32* __restrict__ histS, const u32* __restrict__ keysS,
                                                  int* __restrict__ idx){
  __shared__ u32 part[1024];
  __shared__ u64 sm[CCAP];
  __shared__ u32 thrT, cnt;
  int t = threadIdx.x;
  u32 base = t*64, s = 0;
  for(int j=0;j<64;++j) s += histS[base+j];
  part[t] = s; __syncthreads();
  for(int off=1;off<1024;off<<=1){
    u32 v = (t+off < 1024) ? part[t+off] : 0u;
    __syncthreads(); part[t] += v; __syncthreads();
  }
  u32 above = part[t] - s;
  if(above < (u32)KS && above + s >= (u32)KS){
    u32 cum = above;
    for(int j=63;j>=0;--j){
      u32 c = histS[base+j];
      if(cum + c >= (u32)KS){ thrT = (u32)(base+j) << 16; cnt = 0; break; }
      cum += c;
    }
  }
  __syncthreads();
  u32 T = thrT;
  for(int i=t;i<NM;i+=1024){
    u32 k = keysS[i];
    if(k >= T){
      u32 p = atomicAdd(&cnt, 1u);
      if(p < (u32)CCAP) sm[p] = ((u64)(~k) << 32) | (u32)i;
    }
  }
  __syncthreads();
  u32 n = cnt; if(n > (u32)CCAP) n = CCAP;
  for(int i=t;i<CCAP;i+=1024) if(i >= (int)n) sm[i] = 0xFFFFFFFFFFFFFFFFull;
  __syncthreads();
  for(int k=2;k<=CCAP;k<<=1){
    for(int j=k>>1;j>0;j>>=1){
      for(int i=t;i<CCAP;i+=1024){
        int ixj = i ^ j;
        if(ixj > i){
          bool up = ((i & k) == 0);
          u64 a = sm[i], b = sm[ixj];
          if((a > b) == up){ sm[i] = b; sm[ixj] = a; }
        }
      }
      __syncthreads();
    }
  }
  if(t < KS) idx[t] = (int)(sm[t] & 0xFFFFFFFFu);
}

// ----------------- gather -----------------
__global__ void k_gather(const int* __restrict__ idx,
                         const float* __restrict__ mv, const float* __restrict__ mnv,
                         const float* __restrict__ mrew,
                         const int* __restrict__ aim, const int* __restrict__ ait,
                         const float* __restrict__ amw1, const float* __restrict__ amb1,
                         const float* __restrict__ atw1, const float* __restrict__ atb1,
                         const float* __restrict__ start, const float* __restrict__ x,
                         const float* __restrict__ pos,
                         float* __restrict__ vecs, float* __restrict__ outnext,
                         u16* __restrict__ hm, u16* __restrict__ ht,
                         float* __restrict__ rew, float* __restrict__ outrew){
  int k = blockIdx.x;
  int t = threadIdx.x;
  if(k < KS){
    int row = idx[k];
    const float4* a = (const float4*)(mv  + (size_t)row*HD);
    const float4* b = (const float4*)(mnv + (size_t)row*HD);
    const float4* pz = (const float4*)(pos + (size_t)(2*k+1)*HD);
    float4* vr = (float4*)(vecs + (size_t)(2*k+1)*HD);
    float4* on = (float4*)(outnext + (size_t)k*HD);
    float4 av = a[t], bv = b[t], pv = pz[t];
    av.x += pv.x; av.y += pv.y; av.z += pv.z; av.w += pv.w;
    vr[t] = av; on[t] = bv;
    int am = aim[row], at = ait[row];
    for(int j=t;j<HD;j+=256){
      hm[(size_t)k*HD+j] = f2bf(gelu_f(amw1[(size_t)j*9 + am] + amb1[j]));
      ht[(size_t)k*HD+j] = f2bf(gelu_f(atw1[(size_t)j*4 + at] + atb1[j]));
    }
    if(t == 0){ float r = mrew[row]; rew[k] = r; outrew[k] = r; }
  } else {
    const float4* st = (const float4*)start;
    const float4* xx = (const float4*)x;
    const float4* p0 = (const float4*)pos;
    const float4* p1 = (const float4*)(pos + (size_t)(SQ-1)*HD);
    float4 v0 = st[t], v1 = xx[t], q0 = p0[t], q1 = p1[t];
    v0.x += q0.x; v0.y += q0.y; v0.z += q0.z; v0.w += q0.w;
    v1.x += q1.x; v1.y += q1.y; v1.z += q1.z; v1.w += q1.w;
    ((float4*)vecs)[t] = v0;
    ((float4*)(vecs + (size_t)(SQ-1)*HD))[t] = v1;
  }
}

// ----------------- bf16 MFMA split-K GEMM (global_load_lds, dbuf) -> bf16 partials -----------------
__device__ __forceinline__ void gemm_body(u16* As, u16* Bs, const u16* __restrict__ A, const u16* __restrict__ B,
        u16* __restrict__ P, int M, int N, int K, int S, int nbm, int lda, int tile){
  int bm = (tile % nbm) * 64;
  int tmp = tile / nbm;
  int z  = tmp % S;
  int bn = (tmp / S) * 64;
  int Ks = K / S, kbeg = z*Ks;
  int nk = Ks >> 5;

  int t = threadIdx.x, lane = t & 63, w = t >> 6;
  int srow = w*16 + (lane >> 2);
  int clog = (lane & 3) ^ ((srow >> 1) & 3);
  const u16* ga = A + (size_t)(bm + srow)*lda + kbeg + clog*8;
  const u16* gb = B + (size_t)(bn + srow)*K  + kbeg + clog*8;
  u16* la = As + w*512;
  u16* lb = Bs + w*512;

  int wm = (w >> 1)*32, wn = (w & 1)*32;
  int lr = lane & 15, lg = lane >> 4;
  int r0 = wm + lr, r1 = r0 + 16;
  int c0 = wn + lr, c1 = c0 + 16;
  int aoff0 = r0*32 + ((lg ^ ((r0>>1)&3))*8);
  int aoff1 = r1*32 + ((lg ^ ((r1>>1)&3))*8);
  int boff0 = c0*32 + ((lg ^ ((c0>>1)&3))*8);
  int boff1 = c1*32 + ((lg ^ ((c1>>1)&3))*8);

  f32x4v acc00 = {0,0,0,0}, acc01 = {0,0,0,0}, acc10 = {0,0,0,0}, acc11 = {0,0,0,0};

  gload16(ga, la);
  gload16(gb, lb);
  ga += 32; gb += 32;
  __syncthreads();

  for(int kk = 0; kk < nk; ++kk){
    int cur = (kk & 1) * 2048;
    if(kk + 1 < nk){
      int nxt = 2048 - cur;
      gload16(ga, la + nxt);
      gload16(gb, lb + nxt);
      ga += 32; gb += 32;
    }
    bf16x8 a0 = *(const bf16x8*)&As[cur + aoff0];
    bf16x8 a1 = *(const bf16x8*)&As[cur + aoff1];
    bf16x8 b0 = *(const bf16x8*)&Bs[cur + boff0];
    bf16x8 b1 = *(const bf16x8*)&Bs[cur + boff1];
    acc00 = __builtin_amdgcn_mfma_f32_16x16x32_bf16(a0, b0, acc00, 0, 0, 0);
    acc01 = __builtin_amdgcn_mfma_f32_16x16x32_bf16(a0, b1, acc01, 0, 0, 0);
    acc10 = __builtin_amdgcn_mfma_f32_16x16x32_bf16(a1, b0, acc10, 0, 0, 0);
    acc11 = __builtin_amdgcn_mfma_f32_16x16x32_bf16(a1, b1, acc11, 0, 0, 0);
    __syncthreads();
  }

  size_t zbase = (size_t)z * (size_t)M;
  #pragma unroll
  for(int r=0;r<4;++r){
    int row0 = bm + wm + lg*4 + r;
    int row1 = row0 + 16;
    int cc0 = bn + wn + lr, cc1 = cc0 + 16;
    if(row0 < M){
      P[(zbase+row0)*N + cc0] = f2bf(acc00[r]);
      P[(zbase+row0)*N + cc1] = f2bf(acc01[r]);
    }
    if(row1 < M){
      P[(zbase+row1)*N + cc0] = f2bf(acc10[r]);
      P[(zbase+row1)*N + cc1] = f2bf(acc11[r]);
    }
  }
}

__global__ __launch_bounds__(256) void k_gemm(const u16* __restrict__ A, const u16* __restrict__ B,
        u16* __restrict__ P, int M, int N, int K, int S, int nbm, int lda){
  __shared__ u16 As[4096];
  __shared__ u16 Bs[4096];
  u32 nwg = gridDim.x, orig = blockIdx.x;
  u32 swz = (orig & 7)*(nwg >> 3) + (orig >> 3);
  gemm_body(As, Bs, A, B, P, M, N, K, S, nbm, lda, (int)swz);
}

__global__ __launch_bounds__(256) void k_actgemm(const u16* __restrict__ hm, const u16* __restrict__ ht,
        const u16* __restrict__ amw2, const u16* __restrict__ atw2,
        u16* __restrict__ part, u16* __restrict__ part2){
  __shared__ u16 As[4096];
  __shared__ u16 Bs[4096];
  int which = blockIdx.x >> 8, tile = blockIdx.x & 255;
  gemm_body(As, Bs, which ? ht : hm, which ? atw2 : amw2, which ? part2 : part,
            KS, HD, HD, 8, 2, HD, tile);
}

// ----------------- flat epilogue: sum S_ bf16 slices + bias (+gelu) -----------------
template<int S_, int ACT, bool BFOUT>
__global__ __launch_bounds__(256) void k_finS(const u16* __restrict__ P, const float* __restrict__ bias,
                                              float* __restrict__ C, u16* __restrict__ Cb, int MN4, int Nd){
  int i4 = blockIdx.x*256 + threadIdx.x;
  if(i4 >= MN4) return;
  size_t off = (size_t)i4*4;
  size_t MN = (size_t)MN4*4;
  float4 v = unpk4(*(const u64*)&P[off]);
  #pragma unroll
  for(int z=1;z<S_;++z){
    float4 q = unpk4(*(const u64*)&P[(size_t)z*MN + off]);
    v.x += q.x; v.y += q.y; v.z += q.z; v.w += q.w;
  }
  int j = (i4 % (Nd/4))*4;
  float4 b4 = *(const float4*)&bias[j];
  v.x += b4.x; v.y += b4.y; v.z += b4.z; v.w += b4.w;
  if(ACT == 1){ v.x = gelu_f(v.x); v.y = gelu_f(v.y); v.z = gelu_f(v.z); v.w = gelu_f(v.w); }
  if(BFOUT) *(u64*)&Cb[off] = pk4(v);
  else      *(float4*)&C[off] = v;
}

// ----------------- row finish: sum S_ bf16 slices + bias + residual; LN | copy-out -----------------
template<int S_, bool LN>
__global__ __launch_bounds__(256) void k_finrow(const u16* __restrict__ P, const float* __restrict__ bias,
                                                float* __restrict__ vecs, const float* __restrict__ lw,
                                                const float* __restrict__ lb, u16* __restrict__ lnb,
                                                float* __restrict__ outp, u16* __restrict__ vhin){
  __shared__ float red[256];
  int row = blockIdx.x, t = threadIdx.x;
  int j = t*4;
  float4 v = unpk4(*(const u64*)&P[(size_t)row*HD + j]);
  #pragma unroll
  for(int z=1;z<S_;++z){
    float4 p = unpk4(*(const u64*)&P[((size_t)z*SQ + row)*HD + j]);
    v.x += p.x; v.y += p.y; v.z += p.z; v.w += p.w;
  }
  float4 b4 = *(const float4*)&bias[j];
  float4 r4 = *(const float4*)&vecs[(size_t)row*HD + j];
  v.x += b4.x + r4.x; v.y += b4.y + r4.y; v.z += b4.z + r4.z; v.w += b4.w + r4.w;
  *(float4*)&vecs[(size_t)row*HD + j] = v;
  if(LN){
    red[t] = v.x+v.y+v.z+v.w; __syncthreads();
    for(int o=128;o>0;o>>=1){ if(t<o) red[t]+=red[t+o]; __syncthreads(); }
    float m = red[0]*(1.0f/HD); __syncthreads();
    float dx=v.x-m, dy=v.y-m, dz=v.z-m, dw=v.w-m;
    red[t] = dx*dx+dy*dy+dz*dz+dw*dw; __syncthreads();
    for(int o=128;o>0;o>>=1){ if(t<o) red[t]+=red[t+o]; __syncthreads(); }
    float den = sqrtf(red[0]*(1.0f/HD) + 1e-5f);
    float4 w4 = *(const float4*)&lw[j];
    float4 lb4 = *(const float4*)&lb[j];
    float4 o4;
    o4.x = dx/den*w4.x + lb4.x; o4.y = dy/den*w4.y + lb4.y;
    o4.z = dz/den*w4.z + lb4.z; o4.w = dw/den*w4.w + lb4.w;
    *(u64*)&lnb[(size_t)row*HD + j] = pk4(o4);
  } else {
    if(row >= 1) *(float4*)&outp[(size_t)(row-1)*HD + j] = v;
    if(row & 1){
      int vr = (row-1) >> 1;
      *(u64*)&vhin[(size_t)vr*HD + j] = pk4(v);
    }
  }
}

// ----------------- finav + LN1 -----------------
__global__ __launch_bounds__(256) void k_finavln(const u16* __restrict__ Pm, const u16* __restrict__ Pt,
                                                 const float* __restrict__ bm_, const float* __restrict__ bt_,
                                                 const float* __restrict__ pos, float* __restrict__ vecs,
                                                 const float* __restrict__ lw, const float* __restrict__ lb,
                                                 u16* __restrict__ lnb){
  __shared__ float red[256];
  int row = blockIdx.x, t = threadIdx.x;
  int j = t*4;
  float4 v;
  if(row >= 2 && row <= 256 && ((row & 1) == 0)){
    int k = (row-2) >> 1;
    float4 s = {0,0,0,0};
    #pragma unroll
    for(int z=0;z<8;++z){
      float4 a = unpk4(*(const u64*)&Pm[((size_t)z*KS + k)*HD + j]);
      float4 b = unpk4(*(const u64*)&Pt[((size_t)z*KS + k)*HD + j]);
      s.x += a.x+b.x; s.y += a.y+b.y; s.z += a.z+b.z; s.w += a.w+b.w;
    }
    float4 bm4 = *(const float4*)&bm_[j];
    float4 bt4 = *(const float4*)&bt_[j];
    float4 p4 = *(const float4*)&pos[(size_t)row*HD + j];
    v.x = 0.5f*(s.x + bm4.x + bt4.x) + p4.x;
    v.y = 0.5f*(s.y + bm4.y + bt4.y) + p4.y;
    v.z = 0.5f*(s.z + bm4.z + bt4.z) + p4.z;
    v.w = 0.5f*(s.w + bm4.w + bt4.w) + p4.w;
    *(float4*)&vecs[(size_t)row*HD + j] = v;
  } else {
    v = *(const float4*)&vecs[(size_t)row*HD + j];
  }
  red[t] = v.x+v.y+v.z+v.w; __syncthreads();
  for(int o=128;o>0;o>>=1){ if(t<o) red[t]+=red[t+o]; __syncthreads(); }
  float m = red[0]*(1.0f/HD); __syncthreads();
  float dx=v.x-m, dy=v.y-m, dz=v.z-m, dw=v.w-m;
  red[t] = dx*dx+dy*dy+dz*dz+dw*dw; __syncthreads();
  for(int o=128;o>0;o>>=1){ if(t<o) red[t]+=red[t+o]; __syncthreads(); }
  float den = sqrtf(red[0]*(1.0f/HD) + 1e-5f);
  float4 w4 = *(const float4*)&lw[j];
  float4 lb4 = *(const float4*)&lb[j];
  float4 o4;
  o4.x = dx/den*w4.x + lb4.x; o4.y = dy/den*w4.y + lb4.y;
  o4.z = dz/den*w4.z + lb4.z; o4.w = dw/den*w4.w + lb4.w;
  *(u64*)&lnb[(size_t)row*HD + j] = pk4(o4);
}

// ----------------- attention (bf16 qkv in, bf16 out) -----------------
__global__ void k_attn(const u16* __restrict__ qkv, u16* __restrict__ outp){
  __shared__ float qv[64];
  __shared__ float p[SQ];
  __shared__ float red[256];
  int q = blockIdx.x, h = blockIdx.y, t = threadIdx.x;
  if(t < 64) qv[t] = bf2f(qkv[(size_t)q*3072 + h*64 + t]);
  __syncthreads();
  int nk = q + 1;
  float lmax = -1e30f;
  for(int j=t;j<nk;j+=256){
    const u32* kr = (const u32*)(qkv + (size_t)j*3072 + 1024 + h*64);
    float d = 0.f;
    #pragma unroll
    for(int c2=0;c2<32;++c2){
      u32 pk = kr[c2];
      d += qv[c2*2]   * __uint_as_float(pk << 16);
      d += qv[c2*2+1] * __uint_as_float(pk & 0xFFFF0000u);
    }
    d *= 0.125f;
    p[j] = d;
    lmax = fmaxf(lmax, d);
  }
  red[t] = lmax; __syncthreads();
  for(int o=128;o>0;o>>=1){ if(t<o) red[t] = fmaxf(red[t], red[t+o]); __syncthreads(); }
  float m = red[0];
  __syncthreads();
  float lsum = 0.f;
  for(int j=t;j<nk;j+=256){ float e = expf(p[j]-m); p[j] = e; lsum += e; }
  red[t] = lsum; __syncthreads();
  for(int o=128;o>0;o>>=1){ if(t<o) red[t] += red[t+o]; __syncthreads(); }
  float inv = 1.0f/red[0];
  __syncthreads();
  int d = t & 63, g = t >> 6;
  float acc = 0.f;
  for(int j=g;j<nk;j+=4) acc += p[j]*bf2f(qkv[(size_t)j*3072 + 2048 + h*64 + d]);
  red[t] = acc; __syncthreads();
  if(g == 0){
    float o4 = red[d] + red[64+d] + red[128+d] + red[192+d];
    outp[(size_t)q*HD + h*64 + d] = f2bf(o4*inv);
  }
}

// ----------------- value head finish (fused final outputs) -----------------
__global__ __launch_bounds__(256) void k_vpfin(const u16* __restrict__ P, const float* __restrict__ vb1,
                                               const float* __restrict__ vw2, const float* __restrict__ vb2,
                                               const float* __restrict__ rew, float* __restrict__ outp){
  __shared__ float red[256];
  int r = blockIdx.x, t = threadIdx.x;
  float s = 0.f;
  for(int c4=t;c4<1024;c4+=256){
    float4 v = unpk4(*(const u64*)&P[(size_t)r*4096 + c4*4]);
    #pragma unroll
    for(int z=1;z<4;++z){
      float4 q = unpk4(*(const u64*)&P[((size_t)z*129 + r)*4096 + c4*4]);
      v.x += q.x; v.y += q.y; v.z += q.z; v.w += q.w;
    }
    float4 b4 = *(const float4*)&vb1[c4*4];
    float4 w4 = *(const float4*)&vw2[c4*4];
    s += gelu_f(v.x + b4.x)*w4.x + gelu_f(v.y + b4.y)*w4.y
       + gelu_f(v.z + b4.z)*w4.z + gelu_f(v.w + b4.w)*w4.w;
  }
  red[t]=s; __syncthreads();
  for(int o=128;o>0;o>>=1){ if(t<o) red[t]+=red[t+o]; __syncthreads(); }
  if(t == 0){
    float val = red[0] + vb2[0];
    if(r == KS) outp[OUT_VP] = val;
    else { float d = val - rew[r]; outp[OUT_LOSS + r] = d*d; }
  }
}

extern "C" void kernel_launch(void* const* d_in, const int* in_sizes, int n_in,
                              void* d_out, int out_size, void* d_ws, size_t ws_size,
                              hipStream_t stream){
  const float* x     = (const float*)d_in[0];
  const float* mv    = (const float*)d_in[1];
  const float* mnv   = (const float*)d_in[2];
  const float* surp  = (const float*)d_in[3];
  const float* mrew  = (const float*)d_in[4];
  const float* noise = (const float*)d_in[5];
  const int*   aim   = (const int*)d_in[6];
  const int*   ait   = (const int*)d_in[7];
  const float* start = (const float*)d_in[8];
  const float* pos   = (const float*)d_in[9];
  const float* inW = (const float*)d_in[10]; const float* inB = (const float*)d_in[11];
  const float* oW  = (const float*)d_in[12]; const float* oB  = (const float*)d_in[13];
  const float* l1w = (const float*)d_in[14]; const float* l1b = (const float*)d_in[15];
  const float* l2w = (const float*)d_in[16]; const float* l2b = (const float*)d_in[17];
  const float* f1w = (const float*)d_in[18]; const float* f1b = (const float*)d_in[19];
  const float* f2w = (const float*)d_in[20]; const float* f2b = (const float*)d_in[21];
  const float* amw1= (const float*)d_in[22]; const float* amb1= (const float*)d_in[23];
  const float* amw2= (const float*)d_in[24]; const float* amb2= (const float*)d_in[25];
  const float* atw1= (const float*)d_in[26]; const float* atb1= (const float*)d_in[27];
  const float* atw2= (const float*)d_in[28]; const float* atb2= (const float*)d_in[29];
  const float* vw1 = (const float*)d_in[30]; const float* vb1 = (const float*)d_in[31];
  const float* vw2 = (const float*)d_in[32]; const float* vb2 = (const float*)d_in[33];

  float* out = (float*)d_out;
  char* ws = (char*)d_ws;
  u32*  hist3 = (u32*)(ws+OFF_H3);
  u32*  cnt3  = (u32*)(ws+OFF_C3);
  u32*  histS = (u32*)(ws+OFF_HS);
  u32*  bsum  = (u32*)(ws+OFF_BS);
  u32*  pref3 = (u32*)(ws+OFF_P3);
  u32*  keys3 = (u32*)(ws+OFF_K3);
  u32*  lo3   = (u32*)(ws+OFF_L3);
  u32*  keysS = (u32*)(ws+OFF_KSC);
  int*  idxb  = (int*)(ws+OFF_IDX);
  float* rew  = (float*)(ws+OFF_REW);
  u16*  hm    = (u16*)(ws+OFF_HM);
  u16*  ht    = (u16*)(ws+OFF_HT);
  float* vecs = (float*)(ws+OFF_VECS);
  u16*  lnb   = (u16*)(ws+OFF_LNB);
  u16*  qkvb  = (u16*)(ws+OFF_QKV);
  u16*  attn  = (u16*)(ws+OFF_ATT);
  u16*  ffh   = (u16*)(ws+OFF_FFH);
  u16*  vhin  = (u16*)(ws+OFF_VHIN);
  u16*  wb    = (u16*)(ws+OFF_WB);
  u16*  part  = (u16*)(ws+OFF_PART);
  u16*  part2 = part + (size_t)8*KS*HD;

  u16* inW_bf = wb + WB_IN;
  u16* oW_bf  = wb + WB_O;
  u16* f1w_bf = wb + WB_F1;
  u16* f2w_bf = wb + WB_F2;
  u16* am_bf  = wb + WB_AM;
  u16* at_bf  = wb + WB_AT;
  u16* vh_bf  = wb + WB_VH;

  dim3 b256(256);
  int gN = NM/256;

  // ---- weight conversion + hist zeroing (one kernel) ----
  {
    WCA a;
    const float* srcs[7] = { inW, oW, f1w, f2w, amw2, atw2, vw1 };
    u16* dsts[7] = { inW_bf, oW_bf, f1w_bf, f2w_bf, am_bf, at_bf, vh_bf };
    u32 sizes4[7] = { 4*3*HD*HD/4, 4*HD*HD/4, 4*4*HD*HD/4, 4*4*HD*HD/4, HD*HD/4, HD*HD/4, 4*HD*HD/4 };
    u32 cum = 0;
    for(int j=0;j<7;++j){
      a.seg[j].s = srcs[j]; a.seg[j].d = dsts[j];
      a.seg[j].base4 = cum; cum += sizes4[j]; a.seg[j].end4 = cum;
    }
    a.tot4 = cum;
    a.z = (u32*)ws;
    hipLaunchKernelGGL(k_wconv, dim3((cum + 255)/256), b256, 0, stream, a);
  }

  // ---- scoring / ranking / top-k ----
  hipLaunchKernelGGL(k_simkey, dim3(NM/8), b256, 0, stream, mv, x, surp, noise, keys3, hist3);
  hipLaunchKernelGGL(k_scanA, dim3(192), b256, 0, stream, hist3, bsum);
  hipLaunchKernelGGL(k_scanC, dim3(192), b256, 0, stream, hist3, bsum, pref3);
  hipLaunchKernelGGL(k_scatter3, dim3(gN), b256, 0, stream, keys3, pref3, cnt3, lo3);
  hipLaunchKernelGGL(k_rank3score, dim3(gN), b256, 0, stream, keys3, pref3, lo3, keysS, histS);
  hipLaunchKernelGGL(k_selsort, dim3(1), dim3(1024), 0, stream, histS, keysS, idxb);

  // ---- gather + action MLPs + assembly/LN1 ----
  hipLaunchKernelGGL(k_gather, dim3(KS+1), b256, 0, stream, idxb, mv, mnv, mrew, aim, ait,
                     amw1, amb1, atw1, atb1, start, x, pos,
                     vecs, out + OUT_NEXT, hm, ht, rew, out + OUT_REWO);
  hipLaunchKernelGGL(k_actgemm, dim3(512), b256, 0, stream, hm, ht, am_bf, at_bf, part, part2);
  hipLaunchKernelGGL(k_finavln, dim3(SQ), b256, 0, stream, part, part2, amb2, atb2, pos, vecs, l1w, l1b, lnb);

  // ---- transformer ----
  for(int l=0;l<NL;++l){
    hipLaunchKernelGGL(k_gemm, dim3(480), b256, 0, stream, lnb, inW_bf + (size_t)l*3*HD*HD, part, SQ, 3*HD, HD, 2, 5, HD);
    hipLaunchKernelGGL((k_finS<2,0,true>), dim3(774), b256, 0, stream, part, inB + (size_t)l*3*HD, (float*)nullptr, qkvb, SQ*3*HD/4, 3*HD);
    hipLaunchKernelGGL(k_attn, dim3(SQ, 16), b256, 0, stream, qkvb, attn);
    hipLaunchKernelGGL(k_gemm, dim3(640), b256, 0, stream, attn, oW_bf + (size_t)l*HD*HD, part, SQ, HD, HD, 8, 5, HD);
    hipLaunchKernelGGL((k_finrow<8,true>), dim3(SQ), b256, 0, stream, part, oB + (size_t)l*HD, vecs,
                       l2w + (size_t)l*HD, l2b + (size_t)l*HD, lnb, (float*)nullptr, (u16*)nullptr);
    hipLaunchKernelGGL(k_gemm, dim3(640), b256, 0, stream, lnb, f1w_bf + (size_t)l*4*HD*HD, part, SQ, 4*HD, HD, 2, 5, HD);
    hipLaunchKernelGGL((k_finS<2,1,true>), dim3(1032), b256, 0, stream, part, f1b + (size_t)l*4*HD, (float*)nullptr, ffh, SQ*4*HD/4, 4*HD);
    hipLaunchKernelGGL(k_gemm, dim3(640), b256, 0, stream, ffh, f2w_bf + (size_t)l*HD*4*HD, part, SQ, HD, 4*HD, 8, 5, 4*HD);
    if(l < NL-1)
      hipLaunchKernelGGL((k_finrow<8,true>), dim3(SQ), b256, 0, stream, part, f2b + (size_t)l*HD, vecs,
                         l1w + (size_t)(l+1)*HD, l1b + (size_t)(l+1)*HD, lnb, (float*)nullptr, (u16*)nullptr);
    else
      hipLaunchKernelGGL((k_finrow<8,false>), dim3(SQ), b256, 0, stream, part, f2b + (size_t)l*HD, vecs,
                         (const float*)nullptr, (const float*)nullptr, (u16*)nullptr, out, vhin);
  }

  // ---- value head ----
  hipLaunchKernelGGL(k_gemm, dim3(768), b256, 0, stream, vhin, vh_bf, part, KS+1, 4*HD, HD, 4, 3, HD);
  hipLaunchKernelGGL(k_vpfin, dim3(KS+1), b256, 0, stream, part, vb1, vw2, vb2, rew, out);
}

// Round 10
// 850.491 us; speedup vs baseline: 3.3325x; 1.0382x over previous
//
#include <hip/hip_runtime.h>
#include <hip/hip_bf16.h>
#include <math.h>
#include <stdint.h>

typedef unsigned int u32;
typedef unsigned short u16;
typedef unsigned long long u64;

#define NM   65536
#define HD   1024
#define KS   128
#define SQ   258
#define NL   4
#define NBIN 65536
#define CCAP 2048

using bf16x8 = __attribute__((ext_vector_type(8))) short;
using f32x4v = __attribute__((ext_vector_type(4))) float;

static constexpr size_t A256(size_t x){ return (x + 255) & ~(size_t)255; }

// ---- zeroed region (folded into k_wconv): hist3 + cnt3 + histS = 1792 KB ----
constexpr size_t OFF_H3   = 0;
constexpr size_t OFF_C3   = OFF_H3 + (size_t)3*NBIN*4;
constexpr size_t OFF_HS   = OFF_C3 + (size_t)3*NBIN*4;
constexpr size_t ZERO_BYTES = OFF_HS + (size_t)NBIN*4;
constexpr u32 ZBLK = 1792;
// ---- rest ----
constexpr size_t OFF_BS   = A256(ZERO_BYTES);
constexpr size_t OFF_P3   = A256(OFF_BS + 192*4);
constexpr size_t OFF_K3   = A256(OFF_P3 + (size_t)3*(NBIN+1)*4);
constexpr size_t OFF_L3   = A256(OFF_K3 + (size_t)3*NM*4);            // u16 lo3
constexpr size_t OFF_KSC  = A256(OFF_L3 + (size_t)3*NM*2);
constexpr size_t OFF_IDX  = A256(OFF_KSC + (size_t)NM*4);
constexpr size_t OFF_REW  = A256(OFF_IDX  + (size_t)KS*4);
constexpr size_t OFF_HM   = A256(OFF_REW  + (size_t)KS*4);
constexpr size_t OFF_HT   = A256(OFF_HM   + (size_t)KS*HD*2);
constexpr size_t OFF_VECS = A256(OFF_HT   + (size_t)KS*HD*2);
constexpr size_t OFF_LNB  = A256(OFF_VECS + (size_t)SQ*HD*4);
constexpr size_t OFF_QKV  = A256(OFF_LNB  + (size_t)SQ*HD*2);
constexpr size_t OFF_ATT  = A256(OFF_QKV  + (size_t)SQ*3*HD*2);
constexpr size_t OFF_FFH  = A256(OFF_ATT  + (size_t)SQ*HD*2);
constexpr size_t OFF_VHIN = A256(OFF_FFH  + (size_t)SQ*4*HD*2);
constexpr size_t OFF_WB   = A256(OFF_VHIN + (size_t)129*HD*2);
constexpr size_t NWELEM   = 56623104;
constexpr size_t OFF_PART = A256(OFF_WB + NWELEM*2);

constexpr size_t WB_IN = 0;
constexpr size_t WB_O  = WB_IN + (size_t)4*3*HD*HD;
constexpr size_t WB_F1 = WB_O  + (size_t)4*HD*HD;
constexpr size_t WB_F2 = WB_F1 + (size_t)4*4*HD*HD;
constexpr size_t WB_AM = WB_F2 + (size_t)4*4*HD*HD;
constexpr size_t WB_AT = WB_AM + (size_t)HD*HD;
constexpr size_t WB_VH = WB_AT + (size_t)HD*HD;

// output layout (floats)
constexpr int OUT_NEXT = 257*HD;
constexpr int OUT_VP   = OUT_NEXT + KS*HD;
constexpr int OUT_LOSS = OUT_VP + 1;
constexpr int OUT_REWO = OUT_LOSS + KS;

__device__ __forceinline__ float gelu_f(float v){
  return 0.5f*v*(1.0f + erff(v*0.70710678118654752440f));
}

__device__ __forceinline__ u16 f2bf(float f){
  __hip_bfloat16 h = __float2bfloat16(f);
  u16 s; __builtin_memcpy(&s, &h, sizeof(u16));
  return s;
}

__device__ __forceinline__ float bf2f(u16 v){ return __uint_as_float(((u32)v) << 16); }

__device__ __forceinline__ float4 unpk4(u64 pk){
  u32 lo = (u32)pk, hi = (u32)(pk >> 32);
  float4 v;
  v.x = __uint_as_float(lo << 16);
  v.y = __uint_as_float(lo & 0xFFFF0000u);
  v.z = __uint_as_float(hi << 16);
  v.w = __uint_as_float(hi & 0xFFFF0000u);
  return v;
}

__device__ __forceinline__ u64 pk4(float4 v){
  u16 r[4] = { f2bf(v.x), f2bf(v.y), f2bf(v.z), f2bf(v.w) };
  u64 pk; __builtin_memcpy(&pk, r, 8);
  return pk;
}

__device__ __forceinline__ u32 fkey(float v){
  u32 b = __float_as_uint(v);
  return (b >> 31) ? ~b : (b | 0x80000000u);
}

__device__ __forceinline__ void gload16(const u16* g, u16* l){
  __builtin_amdgcn_global_load_lds(
      (const __attribute__((address_space(1))) unsigned int*)g,
      (__attribute__((address_space(3))) unsigned int*)l, 16, 0, 0);
}

// ----------------- weight conversion fp32 -> bf16 (+ zero hist regions) -----------------
struct WSeg { const float* s; u16* d; u32 base4, end4; };
struct WCA { WSeg seg[7]; u32 tot4; u32* z; };
__global__ __launch_bounds__(256) void k_wconv(WCA a){
  if(blockIdx.x < ZBLK) a.z[blockIdx.x*256 + threadIdx.x] = 0u;
  u32 i = blockIdx.x*256 + threadIdx.x;
  if(i >= a.tot4) return;
  #pragma unroll
  for(int j=0;j<7;++j){
    if(i < a.seg[j].end4){
      u32 off = i - a.seg[j].base4;
      float4 v = *(const float4*)&a.seg[j].s[(size_t)off*4];
      *(u64*)&a.seg[j].d[(size_t)off*4] = pk4(v);
      return;
    }
  }
}

// ----------------- fused xnorm + sim + keys + hist (8 rows/block) -----------------
__global__ __launch_bounds__(256) void k_simkey(const float* __restrict__ mv, const float* __restrict__ x,
                                                const float* __restrict__ surp, const float* __restrict__ noise,
                                                u32* __restrict__ keys3, u32* __restrict__ hist3){
  __shared__ float xs[HD];
  __shared__ float red[256];
  int t = threadIdx.x;
  float s = 0.f;
  for(int i=t;i<HD;i+=256){ float v=x[i]; s += v*v; }
  red[t]=s; __syncthreads();
  for(int o=128;o>0;o>>=1){ if(t<o) red[t]+=red[t+o]; __syncthreads(); }
  float nrm = fmaxf(sqrtf(red[0]), 1e-8f);
  for(int i=t;i<HD;i+=256) xs[i] = x[i]/nrm;
  __syncthreads();
  int lane = t & 63, w = t >> 6;
  #pragma unroll
  for(int rep=0;rep<2;++rep){
    int row = blockIdx.x*8 + rep*4 + w;
    const float4* p = (const float4*)(mv + (size_t)row*HD);
    const float4* q = (const float4*)xs;
    float d=0.f, ss=0.f;
    #pragma unroll
    for(int r=0;r<4;++r){
      float4 v = p[lane + 64*r]; float4 u = q[lane + 64*r];
      d  += v.x*u.x + v.y*u.y + v.z*u.z + v.w*u.w;
      ss += v.x*v.x + v.y*v.y + v.z*v.z + v.w*v.w;
    }
    for(int off=32;off>0;off>>=1){ d += __shfl_xor(d,off,64); ss += __shfl_xor(ss,off,64); }
    if(lane==0){
      float sim = d / fmaxf(sqrtf(ss),1e-8f);
      float vals[3] = { surp[row], sim, noise[row] };
      #pragma unroll
      for(int a=0;a<3;++a){
        u32 k = fkey(vals[a]);
        keys3[(size_t)a*NM + row] = k;
        atomicAdd(&hist3[(size_t)a*NBIN + (k >> 16)], 1u);
      }
    }
  }
}

// ----------------- scan: A (block sums) + C (inline base, per-chunk prefix) -----------------
__global__ __launch_bounds__(256) void k_scanA(const u32* __restrict__ hist3, u32* __restrict__ bsum){
  __shared__ u32 red[256];
  int blk = blockIdx.x;
  int t = threadIdx.x;
  const u32* h = hist3 + (size_t)(blk>>6)*NBIN + (size_t)(blk&63)*1024;
  u32 s = 0;
  #pragma unroll
  for(int j=0;j<4;++j) s += h[t*4+j];
  red[t]=s; __syncthreads();
  for(int o=128;o>0;o>>=1){ if(t<o) red[t]+=red[t+o]; __syncthreads(); }
  if(t==0) bsum[blk] = red[0];
}

__global__ __launch_bounds__(256) void k_scanC(const u32* __restrict__ hist3, const u32* __restrict__ bsum,
                                               u32* __restrict__ pref3){
  __shared__ u32 part[256];
  int blk = blockIdx.x;
  int t = threadIdx.x;
  int a = blk >> 6, c = blk & 63;
  u32 base = 0;
  for(int j=0;j<c;++j) base += bsum[a*64 + j];
  const u32* h = hist3 + (size_t)a*NBIN + (size_t)c*1024;
  u32* pref = pref3 + (size_t)a*(NBIN+1) + (size_t)c*1024;
  u32 loc[4]; u32 s = 0;
  #pragma unroll
  for(int j=0;j<4;++j){ loc[j] = h[t*4+j]; s += loc[j]; }
  part[t] = s; __syncthreads();
  for(int off=1;off<256;off<<=1){
    u32 u = (t >= off) ? part[t-off] : 0u;
    __syncthreads(); part[t] += u; __syncthreads();
  }
  u32 run = base + part[t] - s;
  #pragma unroll
  for(int j=0;j<4;++j){ pref[t*4+j] = run; run += loc[j]; }
  if(c == 63 && t == 255) pref3[(size_t)a*(NBIN+1) + NBIN] = NM;
}

// ----------------- scatter / rank+score -----------------
__global__ void k_scatter3(const u32* __restrict__ keys3, const u32* __restrict__ pref3,
                           u32* __restrict__ cnt3, u16* __restrict__ lo3){
  int i = blockIdx.x*256 + threadIdx.x;
  if(i >= NM) return;
  #pragma unroll
  for(int a=0;a<3;++a){
    u32 k = keys3[(size_t)a*NM + i];
    u32 b = k >> 16;
    u32 pos = pref3[(size_t)a*(NBIN+1) + b] + atomicAdd(&cnt3[(size_t)a*NBIN + b], 1u);
    lo3[(size_t)a*NM + pos] = (u16)(k & 0xFFFFu);
  }
}

__global__ void k_rank3score(const u32* __restrict__ keys3, const u32* __restrict__ pref3,
                             const u16* __restrict__ lo3, u32* __restrict__ keysS, u32* __restrict__ histS){
  int i = blockIdx.x*256 + threadIdx.x;
  if(i >= NM) return;
  float rr[3];
  #pragma unroll
  for(int a=0;a<3;++a){
    u32 k = keys3[(size_t)a*NM + i];
    u32 b = k >> 16, my = k & 0xFFFFu;
    const u32* pref = pref3 + (size_t)a*(NBIN+1);
    const u16* lo = lo3 + (size_t)a*NM;
    u32 s = pref[b], e = pref[b+1];
    u32 nl = 0, ne = 0;
    for(u32 j=s;j<e;++j){ u32 u = lo[j]; nl += (u < my); ne += (u == my); }
    u32 left = s + nl, right = left + ne;
    rr[a] = (float)(left + right - 1) * (1.0f/131072.0f);
  }
  float sc = __fadd_rn(__fadd_rn(__fmul_rn(rr[0],rr[0]), __fmul_rn(rr[1],rr[1])), __fmul_rn(rr[2],rr[2]));
  u32 k = __float_as_uint(sc);
  keysS[i] = k;
  atomicAdd(&histS[k >> 16], 1u);
}

// ----------------- fused threshold + collect + bitonic sort -----------------
__global__ __launch_bounds__(1024) void k_selsort(const u32* __restrict__ histS, const u32* __restrict__ keysS,
                                                  int* __restrict__ idx){
  __shared__ u32 part[1024];
  __shared__ u64 sm[CCAP];
  __shared__ u32 thrT, cnt;
  int t = threadIdx.x;
  u32 base = t*64, s = 0;
  for(int j=0;j<64;++j) s += histS[base+j];
  part[t] = s; __syncthreads();
  for(int off=1;off<1024;off<<=1){
    u32 v = (t+off < 1024) ? part[t+off] : 0u;
    __syncthreads(); part[t] += v; __syncthreads();
  }
  u32 above = part[t] - s;
  if(above < (u32)KS && above + s >= (u32)KS){
    u32 cum = above;
    for(int j=63;j>=0;--j){
      u32 c = histS[base+j];
      if(cum + c >= (u32)KS){ thrT = (u32)(base+j) << 16; cnt = 0; break; }
      cum += c;
    }
  }
  __syncthreads();
  u32 T = thrT;
  for(int i=t;i<NM;i+=1024){
    u32 k = keysS[i];
    if(k >= T){
      u32 p = atomicAdd(&cnt, 1u);
      if(p < (u32)CCAP) sm[p] = ((u64)(~k) << 32) | (u32)i;
    }
  }
  __syncthreads();
  u32 n = cnt; if(n > (u32)CCAP) n = CCAP;
  for(int i=t;i<CCAP;i+=1024) if(i >= (int)n) sm[i] = 0xFFFFFFFFFFFFFFFFull;
  __syncthreads();
  for(int k=2;k<=CCAP;k<<=1){
    for(int j=k>>1;j>0;j>>=1){
      for(int i=t;i<CCAP;i+=1024){
        int ixj = i ^ j;
        if(ixj > i){
          bool up = ((i & k) == 0);
          u64 a = sm[i], b = sm[ixj];
          if((a > b) == up){ sm[i] = b; sm[ixj] = a; }
        }
      }
      __syncthreads();
    }
  }
  if(t < KS) idx[t] = (int)(sm[t] & 0xFFFFFFFFu);
}

// ----------------- gather -----------------
__global__ void k_gather(const int* __restrict__ idx,
                         const float* __restrict__ mv, const float* __restrict__ mnv,
                         const float* __restrict__ mrew,
                         const int* __restrict__ aim, const int* __restrict__ ait,
                         const float* __restrict__ amw1, const float* __restrict__ amb1,
                         const float* __restrict__ atw1, const float* __restrict__ atb1,
                         const float* __restrict__ start, const float* __restrict__ x,
                         const float* __restrict__ pos,
                         float* __restrict__ vecs, float* __restrict__ outnext,
                         u16* __restrict__ hm, u16* __restrict__ ht,
                         float* __restrict__ rew, float* __restrict__ outrew){
  int k = blockIdx.x;
  int t = threadIdx.x;
  if(k < KS){
    int row = idx[k];
    const float4* a = (const float4*)(mv  + (size_t)row*HD);
    const float4* b = (const float4*)(mnv + (size_t)row*HD);
    const float4* pz = (const float4*)(pos + (size_t)(2*k+1)*HD);
    float4* vr = (float4*)(vecs + (size_t)(2*k+1)*HD);
    float4* on = (float4*)(outnext + (size_t)k*HD);
    float4 av = a[t], bv = b[t], pv = pz[t];
    av.x += pv.x; av.y += pv.y; av.z += pv.z; av.w += pv.w;
    vr[t] = av; on[t] = bv;
    int am = aim[row], at = ait[row];
    for(int j=t;j<HD;j+=256){
      hm[(size_t)k*HD+j] = f2bf(gelu_f(amw1[(size_t)j*9 + am] + amb1[j]));
      ht[(size_t)k*HD+j] = f2bf(gelu_f(atw1[(size_t)j*4 + at] + atb1[j]));
    }
    if(t == 0){ float r = mrew[row]; rew[k] = r; outrew[k] = r; }
  } else {
    const float4* st = (const float4*)start;
    const float4* xx = (const float4*)x;
    const float4* p0 = (const float4*)pos;
    const float4* p1 = (const float4*)(pos + (size_t)(SQ-1)*HD);
    float4 v0 = st[t], v1 = xx[t], q0 = p0[t], q1 = p1[t];
    v0.x += q0.x; v0.y += q0.y; v0.z += q0.z; v0.w += q0.w;
    v1.x += q1.x; v1.y += q1.y; v1.z += q1.z; v1.w += q1.w;
    ((float4*)vecs)[t] = v0;
    ((float4*)(vecs + (size_t)(SQ-1)*HD))[t] = v1;
  }
}

// ----------------- bf16 MFMA split-K GEMM, BK=64 (global_load_lds, dbuf) -> bf16 partials -----------------
// LDS layout per buffer: [64 rows][8 chunks of 8 bf16], chunk c holds global chunk c^(row&7).
__device__ __forceinline__ void gemm_body(u16* As, u16* Bs, const u16* __restrict__ A, const u16* __restrict__ B,
        u16* __restrict__ P, int M, int N, int K, int S, int nbm, int lda, int tile){
  int bm = (tile % nbm) * 64;
  int tmp = tile / nbm;
  int z  = tmp % S;
  int bn = (tmp / S) * 64;
  int Ks = K / S, kbeg = z*Ks;
  int nk = Ks >> 6;   // BK=64

  int t = threadIdx.x, lane = t & 63, w = t >> 6;
  // staging: seg s in [0,512): row=s>>3, chunk=s&7; lane handles s0 = w*64+lane, s1 = s0+256
  int s0 = w*64 + lane, s1 = s0 + 256;
  int r0s = s0 >> 3, c0s = (s0 & 7) ^ (r0s & 7);
  int r1s = s1 >> 3, c1s = (s1 & 7) ^ (r1s & 7);
  const u16* ga0 = A + (size_t)(bm + r0s)*lda + kbeg + c0s*8;
  const u16* ga1 = A + (size_t)(bm + r1s)*lda + kbeg + c1s*8;
  const u16* gb0 = B + (size_t)(bn + r0s)*K  + kbeg + c0s*8;
  const u16* gb1 = B + (size_t)(bn + r1s)*K  + kbeg + c1s*8;
  int lb0 = w*512, lb1 = 2048 + w*512;     // wave-uniform LDS bases (u16 units)

  int wm = (w >> 1)*32, wn = (w & 1)*32;
  int lr = lane & 15, lg = lane >> 4;
  int ra0 = wm + lr, ra1 = ra0 + 16;
  int rb0 = wn + lr, rb1 = rb0 + 16;
  // read offsets: row*64 + ((ks*4+lg)^(row&7))*8, for ks=0,1
  int a00 = ra0*64 + ((lg     ^ (ra0&7))*8);
  int a01 = ra0*64 + (((4+lg) ^ (ra0&7))*8);
  int a10 = ra1*64 + ((lg     ^ (ra1&7))*8);
  int a11 = ra1*64 + (((4+lg) ^ (ra1&7))*8);
  int b00 = rb0*64 + ((lg     ^ (rb0&7))*8);
  int b01 = rb0*64 + (((4+lg) ^ (rb0&7))*8);
  int b10 = rb1*64 + ((lg     ^ (rb1&7))*8);
  int b11 = rb1*64 + (((4+lg) ^ (rb1&7))*8);

  f32x4v acc00 = {0,0,0,0}, acc01 = {0,0,0,0}, acc10 = {0,0,0,0}, acc11 = {0,0,0,0};

  gload16(ga0, As + lb0); gload16(ga1, As + lb1);
  gload16(gb0, Bs + lb0); gload16(gb1, Bs + lb1);
  ga0 += 64; ga1 += 64; gb0 += 64; gb1 += 64;
  __syncthreads();

  for(int kk = 0; kk < nk; ++kk){
    int cur = (kk & 1) << 12;
    if(kk + 1 < nk){
      int nxt = cur ^ 4096;
      gload16(ga0, As + nxt + lb0); gload16(ga1, As + nxt + lb1);
      gload16(gb0, Bs + nxt + lb0); gload16(gb1, Bs + nxt + lb1);
      ga0 += 64; ga1 += 64; gb0 += 64; gb1 += 64;
    }
    bf16x8 xa0 = *(const bf16x8*)&As[cur + a00];
    bf16x8 xa1 = *(const bf16x8*)&As[cur + a10];
    bf16x8 xb0 = *(const bf16x8*)&Bs[cur + b00];
    bf16x8 xb1 = *(const bf16x8*)&Bs[cur + b10];
    acc00 = __builtin_amdgcn_mfma_f32_16x16x32_bf16(xa0, xb0, acc00, 0, 0, 0);
    acc01 = __builtin_amdgcn_mfma_f32_16x16x32_bf16(xa0, xb1, acc01, 0, 0, 0);
    acc10 = __builtin_amdgcn_mfma_f32_16x16x32_bf16(xa1, xb0, acc10, 0, 0, 0);
    acc11 = __builtin_amdgcn_mfma_f32_16x16x32_bf16(xa1, xb1, acc11, 0, 0, 0);
    xa0 = *(const bf16x8*)&As[cur + a01];
    xa1 = *(const bf16x8*)&As[cur + a11];
    xb0 = *(const bf16x8*)&Bs[cur + b01];
    xb1 = *(const bf16x8*)&Bs[cur + b11];
    acc00 = __builtin_amdgcn_mfma_f32_16x16x32_bf16(xa0, xb0, acc00, 0, 0, 0);
    acc01 = __builtin_amdgcn_mfma_f32_16x16x32_bf16(xa0, xb1, acc01, 0, 0, 0);
    acc10 = __builtin_amdgcn_mfma_f32_16x16x32_bf16(xa1, xb0, acc10, 0, 0, 0);
    acc11 = __builtin_amdgcn_mfma_f32_16x16x32_bf16(xa1, xb1, acc11, 0, 0, 0);
    __syncthreads();
  }

  size_t zbase = (size_t)z * (size_t)M;
  #pragma unroll
  for(int r=0;r<4;++r){
    int row0 = bm + wm + lg*4 + r;
    int row1 = row0 + 16;
    int cc0 = bn + wn + lr, cc1 = cc0 + 16;
    if(row0 < M){
      P[(zbase+row0)*N + cc0] = f2bf(acc00[r]);
      P[(zbase+row0)*N + cc1] = f2bf(acc01[r]);
    }
    if(row1 < M){
      P[(zbase+row1)*N + cc0] = f2bf(acc10[r]);
      P[(zbase+row1)*N + cc1] = f2bf(acc11[r]);
    }
  }
}

__global__ __launch_bounds__(256) void k_gemm(const u16* __restrict__ A, const u16* __restrict__ B,
        u16* __restrict__ P, int M, int N, int K, int S, int nbm, int lda){
  __shared__ u16 As[8192];
  __shared__ u16 Bs[8192];
  u32 nwg = gridDim.x, orig = blockIdx.x;
  u32 swz = (orig & 7)*(nwg >> 3) + (orig >> 3);
  gemm_body(As, Bs, A, B, P, M, N, K, S, nbm, lda, (int)swz);
}

__global__ __launch_bounds__(256) void k_actgemm(const u16* __restrict__ hm, const u16* __restrict__ ht,
        const u16* __restrict__ amw2, const u16* __restrict__ atw2,
        u16* __restrict__ part, u16* __restrict__ part2){
  __shared__ u16 As[8192];
  __shared__ u16 Bs[8192];
  int which = blockIdx.x >> 8, tile = blockIdx.x & 255;
  gemm_body(As, Bs, which ? ht : hm, which ? atw2 : amw2, which ? part2 : part,
            KS, HD, HD, 8, 2, HD, tile);
}

// ----------------- flat epilogue: sum S_ bf16 slices + bias (+gelu) -----------------
template<int S_, int ACT, bool BFOUT>
__global__ __launch_bounds__(256) void k_finS(const u16* __restrict__ P, const float* __restrict__ bias,
                                              float* __restrict__ C, u16* __restrict__ Cb, int MN4, int Nd){
  int i4 = blockIdx.x*256 + threadIdx.x;
  if(i4 >= MN4) return;
  size_t off = (size_t)i4*4;
  size_t MN = (size_t)MN4*4;
  float4 v = unpk4(*(const u64*)&P[off]);
  #pragma unroll
  for(int z=1;z<S_;++z){
    float4 q = unpk4(*(const u64*)&P[(size_t)z*MN + off]);
    v.x += q.x; v.y += q.y; v.z += q.z; v.w += q.w;
  }
  int j = (i4 % (Nd/4))*4;
  float4 b4 = *(const float4*)&bias[j];
  v.x += b4.x; v.y += b4.y; v.z += b4.z; v.w += b4.w;
  if(ACT == 1){ v.x = gelu_f(v.x); v.y = gelu_f(v.y); v.z = gelu_f(v.z); v.w = gelu_f(v.w); }
  if(BFOUT) *(u64*)&Cb[off] = pk4(v);
  else      *(float4*)&C[off] = v;
}

// ----------------- row finish: sum S_ bf16 slices + bias + residual; LN | copy-out -----------------
template<int S_, bool LN>
__global__ __launch_bounds__(256) void k_finrow(const u16* __restrict__ P, const float* __restrict__ bias,
                                                float* __restrict__ vecs, const float* __restrict__ lw,
                                                const float* __restrict__ lb, u16* __restrict__ lnb,
                                                float* __restrict__ outp, u16* __restrict__ vhin){
  __shared__ float red[256];
  int row = blockIdx.x, t = threadIdx.x;
  int j = t*4;
  float4 v = unpk4(*(const u64*)&P[(size_t)row*HD + j]);
  #pragma unroll
  for(int z=1;z<S_;++z){
    float4 p = unpk4(*(const u64*)&P[((size_t)z*SQ + row)*HD + j]);
    v.x += p.x; v.y += p.y; v.z += p.z; v.w += p.w;
  }
  float4 b4 = *(const float4*)&bias[j];
  float4 r4 = *(const float4*)&vecs[(size_t)row*HD + j];
  v.x += b4.x + r4.x; v.y += b4.y + r4.y; v.z += b4.z + r4.z; v.w += b4.w + r4.w;
  *(float4*)&vecs[(size_t)row*HD + j] = v;
  if(LN){
    red[t] = v.x+v.y+v.z+v.w; __syncthreads();
    for(int o=128;o>0;o>>=1){ if(t<o) red[t]+=red[t+o]; __syncthreads(); }
    float m = red[0]*(1.0f/HD); __syncthreads();
    float dx=v.x-m, dy=v.y-m, dz=v.z-m, dw=v.w-m;
    red[t] = dx*dx+dy*dy+dz*dz+dw*dw; __syncthreads();
    for(int o=128;o>0;o>>=1){ if(t<o) red[t]+=red[t+o]; __syncthreads(); }
    float den = sqrtf(red[0]*(1.0f/HD) + 1e-5f);
    float4 w4 = *(const float4*)&lw[j];
    float4 lb4 = *(const float4*)&lb[j];
    float4 o4;
    o4.x = dx/den*w4.x + lb4.x; o4.y = dy/den*w4.y + lb4.y;
    o4.z = dz/den*w4.z + lb4.z; o4.w = dw/den*w4.w + lb4.w;
    *(u64*)&lnb[(size_t)row*HD + j] = pk4(o4);
  } else {
    if(row >= 1) *(float4*)&outp[(size_t)(row-1)*HD + j] = v;
    if(row & 1){
      int vr = (row-1) >> 1;
      *(u64*)&vhin[(size_t)vr*HD + j] = pk4(v);
    }
  }
}

// ----------------- finav + LN1 -----------------
__global__ __launch_bounds__(256) void k_finavln(const u16* __restrict__ Pm, const u16* __restrict__ Pt,
                                                 const float* __restrict__ bm_, const float* __restrict__ bt_,
                                                 const float* __restrict__ pos, float* __restrict__ vecs,
                                                 const float* __restrict__ lw, const float* __restrict__ lb,
                                                 u16* __restrict__ lnb){
  __shared__ float red[256];
  int row = blockIdx.x, t = threadIdx.x;
  int j = t*4;
  float4 v;
  if(row >= 2 && row <= 256 && ((row & 1) == 0)){
    int k = (row-2) >> 1;
    float4 s = {0,0,0,0};
    #pragma unroll
    for(int z=0;z<8;++z){
      float4 a = unpk4(*(const u64*)&Pm[((size_t)z*KS + k)*HD + j]);
      float4 b = unpk4(*(const u64*)&Pt[((size_t)z*KS + k)*HD + j]);
      s.x += a.x+b.x; s.y += a.y+b.y; s.z += a.z+b.z; s.w += a.w+b.w;
    }
    float4 bm4 = *(const float4*)&bm_[j];
    float4 bt4 = *(const float4*)&bt_[j];
    float4 p4 = *(const float4*)&pos[(size_t)row*HD + j];
    v.x = 0.5f*(s.x + bm4.x + bt4.x) + p4.x;
    v.y = 0.5f*(s.y + bm4.y + bt4.y) + p4.y;
    v.z = 0.5f*(s.z + bm4.z + bt4.z) + p4.z;
    v.w = 0.5f*(s.w + bm4.w + bt4.w) + p4.w;
    *(float4*)&vecs[(size_t)row*HD + j] = v;
  } else {
    v = *(const float4*)&vecs[(size_t)row*HD + j];
  }
  red[t] = v.x+v.y+v.z+v.w; __syncthreads();
  for(int o=128;o>0;o>>=1){ if(t<o) red[t]+=red[t+o]; __syncthreads(); }
  float m = red[0]*(1.0f/HD); __syncthreads();
  float dx=v.x-m, dy=v.y-m, dz=v.z-m, dw=v.w-m;
  red[t] = dx*dx+dy*dy+dz*dz+dw*dw; __syncthreads();
  for(int o=128;o>0;o>>=1){ if(t<o) red[t]+=red[t+o]; __syncthreads(); }
  float den = sqrtf(red[0]*(1.0f/HD) + 1e-5f);
  float4 w4 = *(const float4*)&lw[j];
  float4 lb4 = *(const float4*)&lb[j];
  float4 o4;
  o4.x = dx/den*w4.x + lb4.x; o4.y = dy/den*w4.y + lb4.y;
  o4.z = dz/den*w4.z + lb4.z; o4.w = dw/den*w4.w + lb4.w;
  *(u64*)&lnb[(size_t)row*HD + j] = pk4(o4);
}

// ----------------- attention (bf16 qkv in, bf16 out) -----------------
__global__ void k_attn(const u16* __restrict__ qkv, u16* __restrict__ outp){
  __shared__ float qv[64];
  __shared__ float p[SQ];
  __shared__ float red[256];
  int q = blockIdx.x, h = blockIdx.y, t = threadIdx.x;
  if(t < 64) qv[t] = bf2f(qkv[(size_t)q*3072 + h*64 + t]);
  __syncthreads();
  int nk = q + 1;
  float lmax = -1e30f;
  for(int j=t;j<nk;j+=256){
    const u32* kr = (const u32*)(qkv + (size_t)j*3072 + 1024 + h*64);
    float d = 0.f;
    #pragma unroll
    for(int c2=0;c2<32;++c2){
      u32 pk = kr[c2];
      d += qv[c2*2]   * __uint_as_float(pk << 16);
      d += qv[c2*2+1] * __uint_as_float(pk & 0xFFFF0000u);
    }
    d *= 0.125f;
    p[j] = d;
    lmax = fmaxf(lmax, d);
  }
  red[t] = lmax; __syncthreads();
  for(int o=128;o>0;o>>=1){ if(t<o) red[t] = fmaxf(red[t], red[t+o]); __syncthreads(); }
  float m = red[0];
  __syncthreads();
  float lsum = 0.f;
  for(int j=t;j<nk;j+=256){ float e = expf(p[j]-m); p[j] = e; lsum += e; }
  red[t] = lsum; __syncthreads();
  for(int o=128;o>0;o>>=1){ if(t<o) red[t] += red[t+o]; __syncthreads(); }
  float inv = 1.0f/red[0];
  __syncthreads();
  int d = t & 63, g = t >> 6;
  float acc = 0.f;
  for(int j=g;j<nk;j+=4) acc += p[j]*bf2f(qkv[(size_t)j*3072 + 2048 + h*64 + d]);
  red[t] = acc; __syncthreads();
  if(g == 0){
    float o4 = red[d] + red[64+d] + red[128+d] + red[192+d];
    outp[(size_t)q*HD + h*64 + d] = f2bf(o4*inv);
  }
}

// ----------------- value head finish (fused final outputs) -----------------
__global__ __launch_bounds__(256) void k_vpfin(const u16* __restrict__ P, const float* __restrict__ vb1,
                                               const float* __restrict__ vw2, const float* __restrict__ vb2,
                                               const float* __restrict__ rew, float* __restrict__ outp){
  __shared__ float red[256];
  int r = blockIdx.x, t = threadIdx.x;
  float s = 0.f;
  for(int c4=t;c4<1024;c4+=256){
    float4 v = unpk4(*(const u64*)&P[(size_t)r*4096 + c4*4]);
    #pragma unroll
    for(int z=1;z<4;++z){
      float4 q = unpk4(*(const u64*)&P[((size_t)z*129 + r)*4096 + c4*4]);
      v.x += q.x; v.y += q.y; v.z += q.z; v.w += q.w;
    }
    float4 b4 = *(const float4*)&vb1[c4*4];
    float4 w4 = *(const float4*)&vw2[c4*4];
    s += gelu_f(v.x + b4.x)*w4.x + gelu_f(v.y + b4.y)*w4.y
       + gelu_f(v.z + b4.z)*w4.z + gelu_f(v.w + b4.w)*w4.w;
  }
  red[t]=s; __syncthreads();
  for(int o=128;o>0;o>>=1){ if(t<o) red[t]+=red[t+o]; __syncthreads(); }
  if(t == 0){
    float val = red[0] + vb2[0];
    if(r == KS) outp[OUT_VP] = val;
    else { float d = val - rew[r]; outp[OUT_LOSS + r] = d*d; }
  }
}

extern "C" void kernel_launch(void* const* d_in, const int* in_sizes, int n_in,
                              void* d_out, int out_size, void* d_ws, size_t ws_size,
                              hipStream_t stream){
  const float* x     = (const float*)d_in[0];
  const float* mv    = (const float*)d_in[1];
  const float* mnv   = (const float*)d_in[2];
  const float* surp  = (const float*)d_in[3];
  const float* mrew  = (const float*)d_in[4];
  const float* noise = (const float*)d_in[5];
  const int*   aim   = (const int*)d_in[6];
  const int*   ait   = (const int*)d_in[7];
  const float* start = (const float*)d_in[8];
  const float* pos   = (const float*)d_in[9];
  const float* inW = (const float*)d_in[10]; const float* inB = (const float*)d_in[11];
  const float* oW  = (const float*)d_in[12]; const float* oB  = (const float*)d_in[13];
  const float* l1w = (const float*)d_in[14]; const float* l1b = (const float*)d_in[15];
  const float* l2w = (const float*)d_in[16]; const float* l2b = (const float*)d_in[17];
  const float* f1w = (const float*)d_in[18]; const float* f1b = (const float*)d_in[19];
  const float* f2w = (const float*)d_in[20]; const float* f2b = (const float*)d_in[21];
  const float* amw1= (const float*)d_in[22]; const float* amb1= (const float*)d_in[23];
  const float* amw2= (const float*)d_in[24]; const float* amb2= (const float*)d_in[25];
  const float* atw1= (const float*)d_in[26]; const float* atb1= (const float*)d_in[27];
  const float* atw2= (const float*)d_in[28]; const float* atb2= (const float*)d_in[29];
  const float* vw1 = (const float*)d_in[30]; const float* vb1 = (const float*)d_in[31];
  const float* vw2 = (const float*)d_in[32]; const float* vb2 = (const float*)d_in[33];

  float* out = (float*)d_out;
  char* ws = (char*)d_ws;
  u32*  hist3 = (u32*)(ws+OFF_H3);
  u32*  cnt3  = (u32*)(ws+OFF_C3);
  u32*  histS = (u32*)(ws+OFF_HS);
  u32*  bsum  = (u32*)(ws+OFF_BS);
  u32*  pref3 = (u32*)(ws+OFF_P3);
  u32*  keys3 = (u32*)(ws+OFF_K3);
  u16*  lo3   = (u16*)(ws+OFF_L3);
  u32*  keysS = (u32*)(ws+OFF_KSC);
  int*  idxb  = (int*)(ws+OFF_IDX);
  float* rew  = (float*)(ws+OFF_REW);
  u16*  hm    = (u16*)(ws+OFF_HM);
  u16*  ht    = (u16*)(ws+OFF_HT);
  float* vecs = (float*)(ws+OFF_VECS);
  u16*  lnb   = (u16*)(ws+OFF_LNB);
  u16*  qkvb  = (u16*)(ws+OFF_QKV);
  u16*  attn  = (u16*)(ws+OFF_ATT);
  u16*  ffh   = (u16*)(ws+OFF_FFH);
  u16*  vhin  = (u16*)(ws+OFF_VHIN);
  u16*  wb    = (u16*)(ws+OFF_WB);
  u16*  part  = (u16*)(ws+OFF_PART);
  u16*  part2 = part + (size_t)8*KS*HD;

  u16* inW_bf = wb + WB_IN;
  u16* oW_bf  = wb + WB_O;
  u16* f1w_bf = wb + WB_F1;
  u16* f2w_bf = wb + WB_F2;
  u16* am_bf  = wb + WB_AM;
  u16* at_bf  = wb + WB_AT;
  u16* vh_bf  = wb + WB_VH;

  dim3 b256(256);
  int gN = NM/256;

  // ---- weight conversion + hist zeroing (one kernel) ----
  {
    WCA a;
    const float* srcs[7] = { inW, oW, f1w, f2w, amw2, atw2, vw1 };
    u16* dsts[7] = { inW_bf, oW_bf, f1w_bf, f2w_bf, am_bf, at_bf, vh_bf };
    u32 sizes4[7] = { 4*3*HD*HD/4, 4*HD*HD/4, 4*4*HD*HD/4, 4*4*HD*HD/4, HD*HD/4, HD*HD/4, 4*HD*HD/4 };
    u32 cum = 0;
    for(int j=0;j<7;++j){
      a.seg[j].s = srcs[j]; a.seg[j].d = dsts[j];
      a.seg[j].base4 = cum; cum += sizes4[j]; a.seg[j].end4 = cum;
    }
    a.tot4 = cum;
    a.z = (u32*)ws;
    hipLaunchKernelGGL(k_wconv, dim3((cum + 255)/256), b256, 0, stream, a);
  }

  // ---- scoring / ranking / top-k ----
  hipLaunchKernelGGL(k_simkey, dim3(NM/8), b256, 0, stream, mv, x, surp, noise, keys3, hist3);
  hipLaunchKernelGGL(k_scanA, dim3(192), b256, 0, stream, hist3, bsum);
  hipLaunchKernelGGL(k_scanC, dim3(192), b256, 0, stream, hist3, bsum, pref3);
  hipLaunchKernelGGL(k_scatter3, dim3(gN), b256, 0, stream, keys3, pref3, cnt3, lo3);
  hipLaunchKernelGGL(k_rank3score, dim3(gN), b256, 0, stream, keys3, pref3, lo3, keysS, histS);
  hipLaunchKernelGGL(k_selsort, dim3(1), dim3(1024), 0, stream, histS, keysS, idxb);

  // ---- gather + action MLPs + assembly/LN1 ----
  hipLaunchKernelGGL(k_gather, dim3(KS+1), b256, 0, stream, idxb, mv, mnv, mrew, aim, ait,
                     amw1, amb1, atw1, atb1, start, x, pos,
                     vecs, out + OUT_NEXT, hm, ht, rew, out + OUT_REWO);
  hipLaunchKernelGGL(k_actgemm, dim3(512), b256, 0, stream, hm, ht, am_bf, at_bf, part, part2);
  hipLaunchKernelGGL(k_finavln, dim3(SQ), b256, 0, stream, part, part2, amb2, atb2, pos, vecs, l1w, l1b, lnb);

  // ---- transformer ----
  for(int l=0;l<NL;++l){
    hipLaunchKernelGGL(k_gemm, dim3(480), b256, 0, stream, lnb, inW_bf + (size_t)l*3*HD*HD, part, SQ, 3*HD, HD, 2, 5, HD);
    hipLaunchKernelGGL((k_finS<2,0,true>), dim3(774), b256, 0, stream, part, inB + (size_t)l*3*HD, (float*)nullptr, qkvb, SQ*3*HD/4, 3*HD);
    hipLaunchKernelGGL(k_attn, dim3(SQ, 16), b256, 0, stream, qkvb, attn);
    hipLaunchKernelGGL(k_gemm, dim3(640), b256, 0, stream, attn, oW_bf + (size_t)l*HD*HD, part, SQ, HD, HD, 8, 5, HD);
    hipLaunchKernelGGL((k_finrow<8,true>), dim3(SQ), b256, 0, stream, part, oB + (size_t)l*HD, vecs,
                       l2w + (size_t)l*HD, l2b + (size_t)l*HD, lnb, (float*)nullptr, (u16*)nullptr);
    hipLaunchKernelGGL(k_gemm, dim3(640), b256, 0, stream, lnb, f1w_bf + (size_t)l*4*HD*HD, part, SQ, 4*HD, HD, 2, 5, HD);
    hipLaunchKernelGGL((k_finS<2,1,true>), dim3(1032), b256, 0, stream, part, f1b + (size_t)l*4*HD, (float*)nullptr, ffh, SQ*4*HD/4, 4*HD);
    hipLaunchKernelGGL(k_gemm, dim3(640), b256, 0, stream, ffh, f2w_bf + (size_t)l*HD*4*HD, part, SQ, HD, 4*HD, 8, 5, 4*HD);
    if(l < NL-1)
      hipLaunchKernelGGL((k_finrow<8,true>), dim3(SQ), b256, 0, stream, part, f2b + (size_t)l*HD, vecs,
                         l1w + (size_t)(l+1)*HD, l1b + (size_t)(l+1)*HD, lnb, (float*)nullptr, (u16*)nullptr);
    else
      hipLaunchKernelGGL((k_finrow<8,false>), dim3(SQ), b256, 0, stream, part, f2b + (size_t)l*HD, vecs,
                         (const float*)nullptr, (const float*)nullptr, (u16*)nullptr, out, vhin);
  }

  // ---- value head ----
  hipLaunchKernelGGL(k_gemm, dim3(768), b256, 0, stream, vhin, vh_bf, part, KS+1, 4*HD, HD, 4, 3, HD);
  hipLaunchKernelGGL(k_vpfin, dim3(KS+1), b256, 0, stream, part, vb1, vw2, vb2, rew, out);
}